// Round 3
// baseline (517.158 us; speedup 1.0000x reference)
//
#include <hip/hip_runtime.h>
#include <stdint.h>

typedef short v8s __attribute__((ext_vector_type(8)));
typedef float f4 __attribute__((ext_vector_type(4)));
typedef unsigned short u16;
typedef unsigned int u32;

#define CUT1 19997
#define CUT2 39997
#define CUT3 199997
#define NROWS 1024
#define LDP 1360   // packed proj cols: 1024 + 256 + 64 + 16

__device__ __forceinline__ u32 pack2(float a, float b) {
    return (__float_as_uint(a) >> 16) | (__float_as_uint(b) & 0xffff0000u);
}
__device__ __forceinline__ float b2f(u16 h) { return __uint_as_float(((u32)h) << 16); }
__device__ __forceinline__ u16 f2b(float f) { return (u16)(__float_as_uint(f) >> 16); }

__device__ __forceinline__ void gload16(const void* g, void* l) {
    __builtin_amdgcn_global_load_lds(
        (const __attribute__((address_space(1))) u32*)g,
        (__attribute__((address_space(3))) u32*)l, 16, 0, 0);
}

__device__ __forceinline__ void cast8(const float* __restrict__ in, u16* __restrict__ out, size_t j) {
    const float4* p = (const float4*)(in + j * 8);
    float4 a = p[0], b = p[1];
    uint4 o = { pack2(a.x, a.y), pack2(a.z, a.w), pack2(b.x, b.y), pack2(b.z, b.w) };
    *(uint4*)(out + j * 8) = o;
}

// ======================= fused fp32 -> bf16 cast (hidden + W0..W3) =======================
#define H_E0 131072
#define H_E1 2690688
#define H_E2 3330688
#define H_E3 4610688
__global__ void cast_all_k(const float* __restrict__ hidden,
                           const float* __restrict__ W0, const float* __restrict__ W1,
                           const float* __restrict__ W2, const float* __restrict__ W3,
                           u16* __restrict__ hb, u16* __restrict__ W0b, u16* __restrict__ W1b,
                           u16* __restrict__ W2b, u16* __restrict__ W3b)
{
    int i = blockIdx.x * 256 + threadIdx.x;
    if (i < H_E0) { cast8(hidden, hb, i); return; }
    if (i < H_E1) { cast8(W0, W0b, i - H_E0); return; }
    if (i < H_E2) { cast8(W1, W1b, i - H_E1); return; }
    if (i < H_E3) { cast8(W2, W2b, i - H_E2); return; }
    int r = i - H_E3;
    if (r >= 67738) return;
    // W3 [67738][16] -> bf16 padded to ld=32
    const float4* p = (const float4*)(W3 + (size_t)r * 16);
    float4 a = p[0], b = p[1], c = p[2], d = p[3];
    uint4 o0 = { pack2(a.x, a.y), pack2(a.z, a.w), pack2(b.x, b.y), pack2(b.z, b.w) };
    uint4 o1 = { pack2(c.x, c.y), pack2(c.z, c.w), pack2(d.x, d.y), pack2(d.z, d.w) };
    uint4 z = { 0, 0, 0, 0 };
    uint4* q = (uint4*)(W3b + (size_t)r * 32);
    q[0] = o0; q[1] = o1; q[2] = z; q[3] = z;
}

// ======================= fused transpose: p0..p3 fp32 -> bf16 [1360][1024] =======================
__global__ __launch_bounds__(256) void transpose_all_k(
    const float* __restrict__ p0, const float* __restrict__ p1,
    const float* __restrict__ p2, const float* __restrict__ p3,
    u16* __restrict__ out)
{
    int b = blockIdx.x;
    const float* src; int d, rowOff, bx, by;
    if (b < 1024)      { src = p0; d = 1024; rowOff = 0;    bx = b & 31;          by = b >> 5; }
    else if (b < 1280) { src = p1; d = 256;  rowOff = 1024; bx = (b - 1024) & 7;  by = (b - 1024) >> 3; }
    else if (b < 1344) { src = p2; d = 64;   rowOff = 1280; bx = (b - 1280) & 1;  by = (b - 1280) >> 1; }
    else               { src = p3; d = 16;   rowOff = 1344; bx = 0;               by = b - 1344; }

    __shared__ float tile[32][33];
    int tx = threadIdx.x & 31, ty = threadIdx.x >> 5;
    int x = bx * 32 + tx;
    int ybase = by * 32;
#pragma unroll
    for (int j = 0; j < 4; ++j) {
        int r = ty + j * 8;
        tile[r][tx] = (x < d) ? src[(size_t)(ybase + r) * d + x] : 0.f;
    }
    __syncthreads();
#pragma unroll
    for (int j = 0; j < 4; ++j) {
        int x2 = bx * 32 + ty + j * 8;
        if (x2 < d) out[(size_t)(rowOff + x2) * 1024 + ybase + tx] = f2b(tile[tx][ty + j * 8]);
    }
}

// ======================= MFMA GEMM, conflict-free seg-major LDS =======================
// TN: C[m][n] = sum_k A_bf16[m][k] * B_bf16[n][k]; BM=BN=128; 4 waves 2x2 (64x64 each).
// LDS layout: slot(g=row16grp, seg=k8seg, r=row) = g*(2*BK) + seg*16 + r; 16B per slot.
// MODE 0: store bf16 C. MODE 1: rowsum[m] += sum_n exp(C[m][n] + bias[n]).
// rowmap: optional A-row indirection. count: early-exit rowblocks past roundup(*count,128).
template<int MODE, int BK>
__global__ __launch_bounds__(256) void gemm_k(
    const u16* __restrict__ A, int lda, const int* __restrict__ rowmap,
    const u16* __restrict__ B, int ldb,
    const float* __restrict__ bias, int N, int K,
    u16* __restrict__ Cout, int ldc,
    float* __restrict__ rowsum, const int* __restrict__ count)
{
    constexpr int SLOTS = 16 * BK;       // 16B slots per matrix tile
    constexpr int CALLS = SLOTS / 256;   // gloads per thread per matrix
    constexpr int GS = 2 * BK;           // slots per 16-row group
    constexpr int KH = BK / 32;
    __shared__ __align__(16) u16 As[128 * BK];
    __shared__ __align__(16) u16 Bs[128 * BK];

    const int tid = threadIdx.x;
    const int rbase = blockIdx.x * 128, cbase = blockIdx.y * 128;
    if (count) {
        int cnt = *count;
        if (rbase >= ((cnt + 127) & ~127)) return;
    }

    const int wave = tid >> 6, lane = tid & 63;
    const int l4 = lane & 15, quad = lane >> 4;
    const int wg = (wave >> 1) * 4;   // A row16-group base
    const int cg = (wave & 1) * 4;    // B col16-group base

    const u16* Asrc[CALLS]; u16* Adst[CALLS];
    const u16* Bsrc[CALLS]; u16* Bdst[CALLS];
#pragma unroll
    for (int c2 = 0; c2 < CALLS; ++c2) {
        int s = c2 * 256 + tid;
        int g = s / GS, rem = s % GS;
        int seg = rem >> 4, r = rem & 15;
        int arow = rbase + g * 16 + r;
        if (rowmap) arow = rowmap[arow];
        Asrc[c2] = A + (size_t)arow * lda + seg * 8;
        Adst[c2] = &As[s * 8];
        int bcol = cbase + g * 16 + r; if (bcol >= N) bcol = N - 1;
        Bsrc[c2] = B + (size_t)bcol * ldb + seg * 8;
        Bdst[c2] = &Bs[s * 8];
    }

    f4 acc[4][4] = {};
    for (int kk = 0; kk < K; kk += BK) {
#pragma unroll
        for (int c2 = 0; c2 < CALLS; ++c2) {
            gload16(Asrc[c2] + kk, Adst[c2]);
            gload16(Bsrc[c2] + kk, Bdst[c2]);
        }
        __syncthreads();
#pragma unroll
        for (int kh = 0; kh < KH; ++kh) {
            v8s af[4], bf[4];
#pragma unroll
            for (int r = 0; r < 4; ++r)
                af[r] = *(const v8s*)&As[((wg + r) * GS + (kh * 4 + quad) * 16 + l4) * 8];
#pragma unroll
            for (int c = 0; c < 4; ++c)
                bf[c] = *(const v8s*)&Bs[((cg + c) * GS + (kh * 4 + quad) * 16 + l4) * 8];
#pragma unroll
            for (int r = 0; r < 4; ++r)
#pragma unroll
                for (int c = 0; c < 4; ++c)
                    acc[r][c] = __builtin_amdgcn_mfma_f32_16x16x32_bf16(af[r], bf[c], acc[r][c], 0, 0, 0);
        }
        __syncthreads();
    }

    const int wr = wg * 16, wc = cg * 16;
    if (MODE == 0) {
#pragma unroll
        for (int c = 0; c < 4; ++c) {
            int col = cbase + wc + c * 16 + l4;
            if (col < N) {
#pragma unroll
                for (int r = 0; r < 4; ++r)
#pragma unroll
                    for (int g = 0; g < 4; ++g) {
                        int row = rbase + wr + r * 16 + quad * 4 + g;
                        Cout[(size_t)row * ldc + col] = f2b(acc[r][c][g]);
                    }
            }
        }
    } else {
        float part[4][4];
#pragma unroll
        for (int r = 0; r < 4; ++r)
#pragma unroll
            for (int g = 0; g < 4; ++g) part[r][g] = 0.f;
#pragma unroll
        for (int c = 0; c < 4; ++c) {
            int col = cbase + wc + c * 16 + l4;
            if (col < N) {
                float bb = bias[col];
#pragma unroll
                for (int r = 0; r < 4; ++r)
#pragma unroll
                    for (int g = 0; g < 4; ++g)
                        part[r][g] += __expf(acc[r][c][g] + bb);
            }
        }
#pragma unroll
        for (int off = 1; off < 16; off <<= 1)
#pragma unroll
            for (int r = 0; r < 4; ++r)
#pragma unroll
                for (int g = 0; g < 4; ++g)
                    part[r][g] += __shfl_xor(part[r][g], off);
        float v = part[0][0];
#pragma unroll
        for (int r = 0; r < 4; ++r)
#pragma unroll
            for (int g = 0; g < 4; ++g)
                if (l4 == r * 4 + g) v = part[r][g];
        int row = rbase + wr + (l4 >> 2) * 16 + quad * 4 + (l4 & 3);
        atomicAdd(&rowsum[row], v);
    }
}

// ======================= classify: counts + slot + compacted rowmap =======================
__global__ void classify_k(const int* __restrict__ target, int* __restrict__ cnt,
                           int* __restrict__ slot, int* __restrict__ rowmap) {
    int r = blockIdx.x * 256 + threadIdx.x;
    if (r >= NROWS) return;
    int t = target[r];
    int c = (t < CUT1) ? -1 : (t < CUT2) ? 0 : (t < CUT3) ? 1 : 2;
    int s = -1;
    if (c >= 0) {
        s = atomicAdd(&cnt[c], 1);
        rowmap[c * 1024 + s] = r;
    }
    slot[r] = s;
}

// ======================= fused gather + finalize =======================
__global__ __launch_bounds__(256) void final_k(
    const u16* __restrict__ proj, const int* __restrict__ target, const int* __restrict__ slot,
    const float* __restrict__ cw, const float* __restrict__ cb,
    const float* __restrict__ W0, const float* __restrict__ b0,
    const float* __restrict__ W1, const float* __restrict__ b1,
    const float* __restrict__ W2, const float* __restrict__ b2,
    const float* __restrict__ W3, const float* __restrict__ b3,
    const float* __restrict__ rs, float* __restrict__ out)
{
    int row = blockIdx.x * 4 + (threadIdx.x >> 6);
    int lane = threadIdx.x & 63;
    const u16* pr = proj + (size_t)row * LDP;

    float c0 = 0.f, c1 = 0.f, c2 = 0.f;
    for (int k = lane; k < 1024; k += 64) {
        float pv = b2f(pr[k]);
        c0 += pv * cw[k]; c1 += pv * cw[1024 + k]; c2 += pv * cw[2048 + k];
    }
#pragma unroll
    for (int off = 1; off < 64; off <<= 1) {
        c0 += __shfl_xor(c0, off); c1 += __shfl_xor(c1, off); c2 += __shfl_xor(c2, off);
    }

    int t = target[row];
    const float* W; const float* bb; int K, off, rel;
    if (t < CUT1)      { W = W0; bb = b0; K = 1024; off = 0;    rel = t; }
    else if (t < CUT2) { W = W1; bb = b1; K = 256;  off = 1024; rel = t - CUT1; }
    else if (t < CUT3) { W = W2; bb = b2; K = 64;   off = 1280; rel = t - CUT2; }
    else               { W = W3; bb = b3; K = 16;   off = 1344; rel = t - CUT3; }
    float acc = 0.f;
    const float* wr = W + (size_t)rel * K;
    for (int k = lane; k < K; k += 64) acc += b2f(pr[off + k]) * wr[k];
#pragma unroll
    for (int o2 = 1; o2 < 64; o2 <<= 1) acc += __shfl_xor(acc, o2);

    if (lane == 0) {
        c0 += cb[0]; c1 += cb[1]; c2 += cb[2];
        float tl = acc + bb[rel];
        float lseh = __logf(rs[row] + __expf(c0) + __expf(c1) + __expf(c2));
        float lp;
        if (t < CUT1) lp = tl - lseh;
        else {
            int c = (t < CUT2) ? 0 : (t < CUT3) ? 1 : 2;
            float cc = (c == 0) ? c0 : (c == 1) ? c1 : c2;
            lp = (cc - lseh) + (tl - __logf(rs[(c + 1) * 1024 + slot[row]]));
        }
        out[row] = -lp;
    }
}

// ======================= fallback path (round-1, verified) =======================
__global__ void cast_bf16_k(const float* __restrict__ in, u16* __restrict__ out, int n8) {
    int i = blockIdx.x * 256 + threadIdx.x;
    if (i >= n8) return;
    cast8(in, out, i);
}

__global__ void transpose_f_k(const float* __restrict__ in, float* __restrict__ out, int d, int rowOff) {
    __shared__ float tile[32][33];
    int tx = threadIdx.x, ty = threadIdx.y;
    int x = blockIdx.x * 32 + tx;
    int ybase = blockIdx.y * 32;
#pragma unroll
    for (int j = 0; j < 4; ++j) {
        int r = ty + j * 8;
        tile[r][tx] = (x < d) ? in[(size_t)(ybase + r) * d + x] : 0.f;
    }
    __syncthreads();
#pragma unroll
    for (int j = 0; j < 4; ++j) {
        int x2 = blockIdx.x * 32 + ty + j * 8;
        if (x2 < d) out[(size_t)(rowOff + x2) * 1024 + ybase + tx] = tile[tx][ty + j * 8];
    }
}

__global__ __launch_bounds__(256) void gemm_tn_k(
    const u16* __restrict__ A, int lda,
    const float* __restrict__ B, int ldb,
    const float* __restrict__ bias, int N, int K,
    u16* __restrict__ Cout, int ldc, float* __restrict__ rowsum)
{
    int tid = threadIdx.x;
    int wave = tid >> 6, lane = tid & 63;
    int l4 = lane & 15, quad = lane >> 4;
    int rbase = blockIdx.x * 16;
    int cbase = blockIdx.y * 256 + wave * 64;

    f4 acc[4] = {};
    v8s zero8 = {0, 0, 0, 0, 0, 0, 0, 0};
    const u16* arow = A + (size_t)(rbase + l4) * lda;
    int nk = (K + 31) >> 5;
    for (int kt = 0; kt < nk; ++kt) {
        int kk = (kt << 5) + quad * 8;
        v8s a = (kk < K) ? *(const v8s*)(arow + kk) : zero8;
#pragma unroll
        for (int t = 0; t < 4; ++t) {
            int col = cbase + t * 16 + l4;
            v8s b = zero8;
            if ((col < N) && (kk < K)) {
                const float* bp = B + (size_t)col * ldb + kk;
                float4 f0 = *(const float4*)bp;
                float4 f1 = *(const float4*)(bp + 4);
                union { uint4 u; v8s s; } bu;
                bu.u.x = pack2(f0.x, f0.y); bu.u.y = pack2(f0.z, f0.w);
                bu.u.z = pack2(f1.x, f1.y); bu.u.w = pack2(f1.z, f1.w);
                b = bu.s;
            }
            acc[t] = __builtin_amdgcn_mfma_f32_16x16x32_bf16(a, b, acc[t], 0, 0, 0);
        }
    }
    if (Cout) {
#pragma unroll
        for (int t = 0; t < 4; ++t) {
            int col = cbase + t * 16 + l4;
            if (col < N) {
#pragma unroll
                for (int r = 0; r < 4; ++r)
                    Cout[(size_t)(rbase + quad * 4 + r) * ldc + col] = f2b(acc[t][r]);
            }
        }
    } else {
        float part[4] = {0.f, 0.f, 0.f, 0.f};
#pragma unroll
        for (int t = 0; t < 4; ++t) {
            int col = cbase + t * 16 + l4;
            if (col < N) {
                float bb = bias[col];
#pragma unroll
                for (int r = 0; r < 4; ++r) part[r] += __expf(acc[t][r] + bb);
            }
        }
#pragma unroll
        for (int off = 1; off < 16; off <<= 1)
#pragma unroll
            for (int r = 0; r < 4; ++r) part[r] += __shfl_xor(part[r], off);
        if (l4 < 4) {
            float v = (l4 == 0) ? part[0] : (l4 == 1) ? part[1] : (l4 == 2) ? part[2] : part[3];
            atomicAdd(&rowsum[rbase + quad * 4 + l4], v);
        }
    }
}

__global__ __launch_bounds__(256) void gather_k(
    const u16* __restrict__ proj, const int* __restrict__ target,
    const float* __restrict__ cw, const float* __restrict__ cb,
    const float* __restrict__ W0, const float* __restrict__ b0,
    const float* __restrict__ W1, const float* __restrict__ b1,
    const float* __restrict__ W2, const float* __restrict__ b2,
    const float* __restrict__ W3, const float* __restrict__ b3,
    float* __restrict__ rs_head, float* __restrict__ cl, float* __restrict__ tl)
{
    int row = blockIdx.x * 4 + (threadIdx.x >> 6);
    int lane = threadIdx.x & 63;
    const u16* pr = proj + (size_t)row * LDP;

    float c0 = 0.f, c1 = 0.f, c2 = 0.f;
    for (int k = lane; k < 1024; k += 64) {
        float pv = b2f(pr[k]);
        c0 += pv * cw[k]; c1 += pv * cw[1024 + k]; c2 += pv * cw[2048 + k];
    }
#pragma unroll
    for (int off = 1; off < 64; off <<= 1) {
        c0 += __shfl_xor(c0, off); c1 += __shfl_xor(c1, off); c2 += __shfl_xor(c2, off);
    }
    int t = target[row];
    const float* W; const float* bb; int K, off, rel;
    if (t < CUT1)      { W = W0; bb = b0; K = 1024; off = 0;    rel = t; }
    else if (t < CUT2) { W = W1; bb = b1; K = 256;  off = 1024; rel = t - CUT1; }
    else if (t < CUT3) { W = W2; bb = b2; K = 64;   off = 1280; rel = t - CUT2; }
    else               { W = W3; bb = b3; K = 16;   off = 1344; rel = t - CUT3; }
    float acc = 0.f;
    const float* wr = W + (size_t)rel * K;
    for (int k = lane; k < K; k += 64) acc += b2f(pr[off + k]) * wr[k];
#pragma unroll
    for (int o2 = 1; o2 < 64; o2 <<= 1) acc += __shfl_xor(acc, o2);
    if (lane == 0) {
        c0 += cb[0]; c1 += cb[1]; c2 += cb[2];
        cl[row * 3 + 0] = c0; cl[row * 3 + 1] = c1; cl[row * 3 + 2] = c2;
        atomicAdd(&rs_head[row], __expf(c0) + __expf(c1) + __expf(c2));
        tl[row] = acc + bb[rel];
    }
}

__global__ void finalize_full_k(const int* __restrict__ target, const float* __restrict__ rs,
                                const float* __restrict__ cl, const float* __restrict__ tl,
                                float* __restrict__ out)
{
    int i = blockIdx.x * 256 + threadIdx.x;
    if (i >= NROWS) return;
    int t = target[i];
    float lseh = __logf(rs[i]);
    float lp;
    if (t < CUT1) lp = tl[i] - lseh;
    else {
        int c = (t < CUT2) ? 0 : (t < CUT3) ? 1 : 2;
        lp = (cl[i * 3 + c] - lseh) + (tl[i] - __logf(rs[(c + 1) * 1024 + i]));
    }
    out[i] = -lp;
}

// ======================= host =======================
extern "C" void kernel_launch(void* const* d_in, const int* in_sizes, int n_in,
                              void* d_out, int out_size, void* d_ws, size_t ws_size,
                              hipStream_t stream)
{
    const float* hidden = (const float*)d_in[0];
    const int*   target = (const int*)d_in[1];
    const float* W0 = (const float*)d_in[2];
    const float* b0 = (const float*)d_in[3];
    const float* p0 = (const float*)d_in[4];
    const float* W1 = (const float*)d_in[5];
    const float* b1 = (const float*)d_in[6];
    const float* p1 = (const float*)d_in[7];
    const float* W2 = (const float*)d_in[8];
    const float* b2 = (const float*)d_in[9];
    const float* p2 = (const float*)d_in[10];
    const float* W3 = (const float*)d_in[11];
    const float* b3 = (const float*)d_in[12];
    const float* p3 = (const float*)d_in[13];
    const float* cw = (const float*)d_in[14];
    const float* cb = (const float*)d_in[15];
    float* out = (float*)d_out;
    char* w = (char*)d_ws;

    if (ws_size >= 84000000ull) {
        // ---- fast path ----
        u16*   hb   = (u16*)(w + 0);             // 1024x1024 bf16
        u16*   pTb  = (u16*)(w + 2097152);       // [1360][1024] bf16
        u16*   proj = (u16*)(w + 4882432);       // [1024][1360] bf16
        u16*   W0b  = (u16*)(w + 7667712);       // 19997x1024
        u16*   W1b  = (u16*)(w + 48621568);      // 20000x256
        u16*   W2b  = (u16*)(w + 58861568);      // 160000x64
        u16*   W3b  = (u16*)(w + 79341568);      // 67738x32 (zero-padded k16..31)
        float* rs   = (float*)(w + 83676800);    // 4x1024
        int*   cnt  = (int*)(w + 83693184);      // 3 (+pad)
        int*   slot = (int*)(w + 83693200);      // 1024
        int*   rmap = (int*)(w + 83697296);      // 3x1024
        // zero rs, cnt, slot, rowmap in one memset
        hipMemsetAsync(w + 83676800, 0, 32784, stream);

        cast_all_k<<<18276, 256, 0, stream>>>(hidden, W0, W1, W2, W3, hb, W0b, W1b, W2b, W3b);
        transpose_all_k<<<1376, 256, 0, stream>>>(p0, p1, p2, p3, pTb);
        classify_k<<<4, 256, 0, stream>>>(target, cnt, slot, rmap);

        // proj = hidden @ [p0|p1|p2|p3], bf16 out
        gemm_k<0, 64><<<dim3(8, 11), 256, 0, stream>>>(hb, 1024, nullptr, pTb, 1024, nullptr,
                                                       1360, 1024, proj, LDP, nullptr, nullptr);
        // head sumexp (all rows)
        gemm_k<1, 64><<<dim3(8, 157), 256, 0, stream>>>(proj, LDP, nullptr, W0b, 1024, b0,
                                                        CUT1, 1024, nullptr, 0, rs, nullptr);
        // tails: row-indirect compacted, early-exit via cnt
        gemm_k<1, 64><<<dim3(8, 157), 256, 0, stream>>>(proj + 1024, LDP, rmap, W1b, 256, b1,
                                                        20000, 256, nullptr, 0, rs + 1024, cnt + 0);
        gemm_k<1, 64><<<dim3(8, 1250), 256, 0, stream>>>(proj + 1280, LDP, rmap + 1024, W2b, 64, b2,
                                                         160000, 64, nullptr, 0, rs + 2048, cnt + 1);
        gemm_k<1, 32><<<dim3(8, 530), 256, 0, stream>>>(proj + 1344, LDP, rmap + 2048, W3b, 32, b3,
                                                        67738, 32, nullptr, 0, rs + 3072, cnt + 2);

        final_k<<<256, 256, 0, stream>>>(proj, target, slot, cw, cb,
                                         W0, b0, W1, b1, W2, b2, W3, b3, rs, out);
    } else {
        // ---- round-1 verified fallback ----
        float* pT   = (float*)w;                          // [1360][1024] f32
        u16*   hb   = (u16*)(w + 5570560);                // [1024][1024] bf16
        u16*   proj = (u16*)(w + 7667712);                // [1024][1360] bf16
        float* rs   = (float*)(w + 10452992);
        float* cl   = (float*)(w + 10469376);
        float* tl   = (float*)(w + 10481664);
        dim3 tb(32, 8);

        hipMemsetAsync(rs, 0, 4 * 1024 * sizeof(float), stream);
        cast_bf16_k<<<512, 256, 0, stream>>>(hidden, hb, 131072);
        transpose_f_k<<<dim3(32, 32), tb, 0, stream>>>(p0, pT, 1024, 0);
        transpose_f_k<<<dim3(8, 32),  tb, 0, stream>>>(p1, pT, 256, 1024);
        transpose_f_k<<<dim3(2, 32),  tb, 0, stream>>>(p2, pT, 64, 1280);
        transpose_f_k<<<dim3(1, 32),  tb, 0, stream>>>(p3, pT, 16, 1344);

        gemm_tn_k<<<dim3(64, 6), 256, 0, stream>>>(hb, 1024, pT, 1024, nullptr,
                                                   1360, 1024, proj, LDP, nullptr);
        gemm_tn_k<<<dim3(64, 79), 256, 0, stream>>>(proj, LDP, W0, 1024, b0,
                                                    CUT1, 1024, nullptr, 0, rs);
        gemm_tn_k<<<dim3(64, 79), 256, 0, stream>>>(proj + 1024, LDP, W1, 256, b1,
                                                    20000, 256, nullptr, 0, rs + 1024);
        gemm_tn_k<<<dim3(64, 625), 256, 0, stream>>>(proj + 1280, LDP, W2, 64, b2,
                                                     160000, 64, nullptr, 0, rs + 2048);
        gemm_tn_k<<<dim3(64, 265), 256, 0, stream>>>(proj + 1344, LDP, W3, 16, b3,
                                                     67738, 16, nullptr, 0, rs + 3072);

        gather_k<<<256, 256, 0, stream>>>(proj, target, cw, cb,
                                          W0, b0, W1, b1, W2, b2, W3, b3, rs, cl, tl);
        finalize_full_k<<<4, 256, 0, stream>>>(target, rs, cl, tl, out);
    }
}

// Round 4
// 443.188 us; speedup vs baseline: 1.1669x; 1.1669x over previous
//
#include <hip/hip_runtime.h>
#include <stdint.h>

typedef short v8s __attribute__((ext_vector_type(8)));
typedef float f4 __attribute__((ext_vector_type(4)));
typedef unsigned short u16;
typedef unsigned int u32;

#define CUT1 19997
#define CUT2 39997
#define CUT3 199997
#define NROWS 1024
#define LDP 1360   // packed proj cols: 1024 + 256 + 64 + 16

__device__ __forceinline__ u32 pack2(float a, float b) {
    return (__float_as_uint(a) >> 16) | (__float_as_uint(b) & 0xffff0000u);
}
__device__ __forceinline__ float b2f(u16 h) { return __uint_as_float(((u32)h) << 16); }
__device__ __forceinline__ u16 f2b(float f) { return (u16)(__float_as_uint(f) >> 16); }

__device__ __forceinline__ void gload16(const void* g, void* l) {
    __builtin_amdgcn_global_load_lds(
        (const __attribute__((address_space(1))) u32*)g,
        (__attribute__((address_space(3))) u32*)l, 16, 0, 0);
}

__device__ __forceinline__ void cast8(const float* __restrict__ in, u16* __restrict__ out, size_t j) {
    const float4* p = (const float4*)(in + j * 8);
    float4 a = p[0], b = p[1];
    uint4 o = { pack2(a.x, a.y), pack2(a.z, a.w), pack2(b.x, b.y), pack2(b.z, b.w) };
    *(uint4*)(out + j * 8) = o;
}

// ======================= fused prep: casts + transpose + classify =======================
// blocks [0,18276): fp32->bf16 casts (hidden, W0..W3); [18276,19652): p-transpose;
// block 19652: classify targets + zero rs/rowmap.
#define H_E0 131072
#define H_E1 2690688
#define H_E2 3330688
#define H_E3 4610688
#define PREP_CAST_BLKS 18276
#define PREP_TR_BLKS 1376
__global__ __launch_bounds__(256) void prep_k(
    const float* __restrict__ hidden,
    const float* __restrict__ W0, const float* __restrict__ W1,
    const float* __restrict__ W2, const float* __restrict__ W3,
    const float* __restrict__ p0, const float* __restrict__ p1,
    const float* __restrict__ p2, const float* __restrict__ p3,
    const int* __restrict__ target,
    u16* __restrict__ hb, u16* __restrict__ W0b, u16* __restrict__ W1b,
    u16* __restrict__ W2b, u16* __restrict__ W3b, u16* __restrict__ pTb,
    float* __restrict__ rs, int* __restrict__ cnt, int* __restrict__ slot,
    int* __restrict__ rowmap)
{
    int bid = blockIdx.x;
    int tid = threadIdx.x;

    if (bid < PREP_CAST_BLKS) {
        int i = bid * 256 + tid;
        if (i < H_E0) { cast8(hidden, hb, i); return; }
        if (i < H_E1) { cast8(W0, W0b, i - H_E0); return; }
        if (i < H_E2) { cast8(W1, W1b, i - H_E1); return; }
        if (i < H_E3) { cast8(W2, W2b, i - H_E2); return; }
        int r = i - H_E3;
        if (r >= 67738) return;
        // W3 [67738][16] -> bf16 padded to ld=32
        const float4* p = (const float4*)(W3 + (size_t)r * 16);
        float4 a = p[0], b = p[1], c = p[2], d = p[3];
        uint4 o0 = { pack2(a.x, a.y), pack2(a.z, a.w), pack2(b.x, b.y), pack2(b.z, b.w) };
        uint4 o1 = { pack2(c.x, c.y), pack2(c.z, c.w), pack2(d.x, d.y), pack2(d.z, d.w) };
        uint4 z = { 0, 0, 0, 0 };
        uint4* q = (uint4*)(W3b + (size_t)r * 32);
        q[0] = o0; q[1] = o1; q[2] = z; q[3] = z;
        return;
    }

    if (bid < PREP_CAST_BLKS + PREP_TR_BLKS) {
        int b = bid - PREP_CAST_BLKS;
        const float* src; int d, rowOff, bx, by;
        if (b < 1024)      { src = p0; d = 1024; rowOff = 0;    bx = b & 31;          by = b >> 5; }
        else if (b < 1280) { src = p1; d = 256;  rowOff = 1024; bx = (b - 1024) & 7;  by = (b - 1024) >> 3; }
        else if (b < 1344) { src = p2; d = 64;   rowOff = 1280; bx = (b - 1280) & 1;  by = (b - 1280) >> 1; }
        else               { src = p3; d = 16;   rowOff = 1344; bx = 0;               by = b - 1344; }
        __shared__ float tile[32][33];
        int tx = tid & 31, ty = tid >> 5;
        int x = bx * 32 + tx;
        int ybase = by * 32;
#pragma unroll
        for (int j = 0; j < 4; ++j) {
            int r = ty + j * 8;
            tile[r][tx] = (x < d) ? src[(size_t)(ybase + r) * d + x] : 0.f;
        }
        __syncthreads();
#pragma unroll
        for (int j = 0; j < 4; ++j) {
            int x2 = bx * 32 + ty + j * 8;
            if (x2 < d) pTb[(size_t)(rowOff + x2) * 1024 + ybase + tx] = f2b(tile[tx][ty + j * 8]);
        }
        return;
    }

    // ---- classify block (single block): zero rs + rowmap, bucket targets ----
    __shared__ int lcnt[3];
    for (int i = tid; i < 4096; i += 256) rs[i] = 0.f;
    for (int i = tid; i < 3072; i += 256) rowmap[i] = 0;
    if (tid < 3) lcnt[tid] = 0;
    __syncthreads();
    for (int r = tid; r < NROWS; r += 256) {
        int t = target[r];
        int c = (t < CUT1) ? -1 : (t < CUT2) ? 0 : (t < CUT3) ? 1 : 2;
        int s = -1;
        if (c >= 0) {
            s = atomicAdd(&lcnt[c], 1);
            rowmap[c * 1024 + s] = r;
        }
        slot[r] = s;
    }
    __syncthreads();
    if (tid < 3) cnt[tid] = lcnt[tid];
}

// ======================= MFMA GEMM body, BK=32, seg-major conflict-free LDS =======================
// TN: C[m][n] = sum_k A_bf16[m][k] * B_bf16[n][k]; BM=BN=128; 4 waves 2x2 (64x64 each).
// LDS slot(g=row16grp, seg=k8seg, r=row) = g*64 + seg*16 + r; 16B per slot.
// MODE 0: store bf16 C. MODE 1: rowsum[m] += sum_n exp(C[m][n] + bias[n]).
template<int MODE>
__device__ __forceinline__ void gemm_body(
    const u16* __restrict__ A, int lda, const int* __restrict__ rowmap,
    const u16* __restrict__ B, int ldb,
    const float* __restrict__ bias, int N, int K,
    u16* __restrict__ Cout, int ldc,
    float* __restrict__ rowsum, const int* __restrict__ count,
    int bx, int by)
{
    __shared__ __align__(16) u16 As[4096];
    __shared__ __align__(16) u16 Bs[4096];

    const int tid = threadIdx.x;
    const int rbase = bx * 128, cbase = by * 128;
    if (MODE == 1 && count) {
        int c = *count;
        if (rbase >= ((c + 127) & ~127)) return;
    }

    const int wave = tid >> 6, lane = tid & 63;
    const int l4 = lane & 15, quad = lane >> 4;
    const int wg = (wave >> 1) * 4;   // A row16-group base
    const int cg = (wave & 1) * 4;    // B col16-group base

    // staging addresses: slots {tid, 256+tid}
    const u16 *Asrc0, *Asrc1, *Bsrc0, *Bsrc1;
    {
        int s0 = tid, s1 = 256 + tid;
        int g0 = s0 >> 6, seg0 = (s0 >> 4) & 3, r0 = s0 & 15;
        int g1 = s1 >> 6, seg1 = (s1 >> 4) & 3, r1 = s1 & 15;
        int ar0 = rbase + g0 * 16 + r0, ar1 = rbase + g1 * 16 + r1;
        if (rowmap) { ar0 = rowmap[ar0]; ar1 = rowmap[ar1]; }
        Asrc0 = A + (size_t)ar0 * lda + seg0 * 8;
        Asrc1 = A + (size_t)ar1 * lda + seg1 * 8;
        int bc0 = cbase + g0 * 16 + r0; if (bc0 >= N) bc0 = N - 1;
        int bc1 = cbase + g1 * 16 + r1; if (bc1 >= N) bc1 = N - 1;
        Bsrc0 = B + (size_t)bc0 * ldb + seg0 * 8;
        Bsrc1 = B + (size_t)bc1 * ldb + seg1 * 8;
    }
    u16* Ad0 = &As[tid * 8]; u16* Ad1 = &As[(256 + tid) * 8];
    u16* Bd0 = &Bs[tid * 8]; u16* Bd1 = &Bs[(256 + tid) * 8];

    f4 acc[4][4] = {};
    for (int kk = 0; kk < K; kk += 32) {
        gload16(Asrc0 + kk, Ad0);
        gload16(Asrc1 + kk, Ad1);
        gload16(Bsrc0 + kk, Bd0);
        gload16(Bsrc1 + kk, Bd1);
        __syncthreads();
        v8s af[4], bf[4];
#pragma unroll
        for (int r = 0; r < 4; ++r)
            af[r] = *(const v8s*)&As[((wg + r) * 64 + quad * 16 + l4) * 8];
#pragma unroll
        for (int c = 0; c < 4; ++c)
            bf[c] = *(const v8s*)&Bs[((cg + c) * 64 + quad * 16 + l4) * 8];
#pragma unroll
        for (int r = 0; r < 4; ++r)
#pragma unroll
            for (int c = 0; c < 4; ++c)
                acc[r][c] = __builtin_amdgcn_mfma_f32_16x16x32_bf16(af[r], bf[c], acc[r][c], 0, 0, 0);
        __syncthreads();
    }

    const int wr = wg * 16, wc = cg * 16;
    if (MODE == 0) {
#pragma unroll
        for (int c = 0; c < 4; ++c) {
            int col = cbase + wc + c * 16 + l4;
            if (col < N) {
#pragma unroll
                for (int r = 0; r < 4; ++r)
#pragma unroll
                    for (int g = 0; g < 4; ++g) {
                        int row = rbase + wr + r * 16 + quad * 4 + g;
                        Cout[(size_t)row * ldc + col] = f2b(acc[r][c][g]);
                    }
            }
        }
    } else {
        float part[4][4];
#pragma unroll
        for (int r = 0; r < 4; ++r)
#pragma unroll
            for (int g = 0; g < 4; ++g) part[r][g] = 0.f;
#pragma unroll
        for (int c = 0; c < 4; ++c) {
            int col = cbase + wc + c * 16 + l4;
            if (col < N) {
                float bb = bias[col];
#pragma unroll
                for (int r = 0; r < 4; ++r)
#pragma unroll
                    for (int g = 0; g < 4; ++g)
                        part[r][g] += __expf(acc[r][c][g] + bb);
            }
        }
#pragma unroll
        for (int off = 1; off < 16; off <<= 1)
#pragma unroll
            for (int r = 0; r < 4; ++r)
#pragma unroll
                for (int g = 0; g < 4; ++g)
                    part[r][g] += __shfl_xor(part[r][g], off);
        float v = part[0][0];
#pragma unroll
        for (int r = 0; r < 4; ++r)
#pragma unroll
            for (int g = 0; g < 4; ++g)
                if (l4 == r * 4 + g) v = part[r][g];
        int row = rbase + wr + (l4 >> 2) * 16 + quad * 4 + (l4 & 3);
        atomicAdd(&rowsum[row], v);
    }
}

// ---- proj = hidden @ [p0|p1|p2|p3], bf16 out; grid 8x11 linearized = 88 ----
__global__ __launch_bounds__(256) void proj_gemm_k(
    const u16* __restrict__ hb, const u16* __restrict__ pTb, u16* __restrict__ proj)
{
    int bid = blockIdx.x;
    gemm_body<0>(hb, 1024, nullptr, pTb, 1024, nullptr, 1360, 1024,
                 proj, LDP, nullptr, nullptr, bid & 7, bid >> 3);
}

// ---- fused sumexp over head + 3 tails, one dispatch ----
// regions: [0,1256) head; [1256,2512) tail1; [2512,12512) tail2; [12512,16752) tail3
#define SE_GRID 16752
__global__ __launch_bounds__(256) void sumexp_k(
    const u16* __restrict__ proj,
    const u16* __restrict__ W0b, const u16* __restrict__ W1b,
    const u16* __restrict__ W2b, const u16* __restrict__ W3b,
    const float* __restrict__ b0, const float* __restrict__ b1,
    const float* __restrict__ b2, const float* __restrict__ b3,
    float* __restrict__ rs, const int* __restrict__ rmap, const int* __restrict__ cnt)
{
    int bid = blockIdx.x;
    const u16 *A, *B; const float* bias; float* rsum;
    const int *rm, *cn; int N, K, ldb, rel;
    if (bid < 1256) {
        A = proj;        rm = nullptr;     cn = nullptr;  B = W0b; ldb = 1024;
        bias = b0; N = CUT1;   K = 1024; rsum = rs;        rel = bid;
    } else if (bid < 2512) {
        A = proj + 1024; rm = rmap;        cn = cnt;      B = W1b; ldb = 256;
        bias = b1; N = 20000;  K = 256;  rsum = rs + 1024; rel = bid - 1256;
    } else if (bid < 12512) {
        A = proj + 1280; rm = rmap + 1024; cn = cnt + 1;  B = W2b; ldb = 64;
        bias = b2; N = 160000; K = 64;   rsum = rs + 2048; rel = bid - 2512;
    } else {
        A = proj + 1344; rm = rmap + 2048; cn = cnt + 2;  B = W3b; ldb = 32;
        bias = b3; N = 67738;  K = 32;   rsum = rs + 3072; rel = bid - 12512;
    }
    gemm_body<1>(A, LDP, rm, B, ldb, bias, N, K, nullptr, 0, rsum, cn, rel & 7, rel >> 3);
}

// ======================= fused gather + finalize =======================
__global__ __launch_bounds__(256) void final_k(
    const u16* __restrict__ proj, const int* __restrict__ target, const int* __restrict__ slot,
    const float* __restrict__ cw, const float* __restrict__ cb,
    const float* __restrict__ W0, const float* __restrict__ b0,
    const float* __restrict__ W1, const float* __restrict__ b1,
    const float* __restrict__ W2, const float* __restrict__ b2,
    const float* __restrict__ W3, const float* __restrict__ b3,
    const float* __restrict__ rs, float* __restrict__ out)
{
    int row = blockIdx.x * 4 + (threadIdx.x >> 6);
    int lane = threadIdx.x & 63;
    const u16* pr = proj + (size_t)row * LDP;

    float c0 = 0.f, c1 = 0.f, c2 = 0.f;
    for (int k = lane; k < 1024; k += 64) {
        float pv = b2f(pr[k]);
        c0 += pv * cw[k]; c1 += pv * cw[1024 + k]; c2 += pv * cw[2048 + k];
    }
#pragma unroll
    for (int off = 1; off < 64; off <<= 1) {
        c0 += __shfl_xor(c0, off); c1 += __shfl_xor(c1, off); c2 += __shfl_xor(c2, off);
    }

    int t = target[row];
    const float* W; const float* bb; int K, off, rel;
    if (t < CUT1)      { W = W0; bb = b0; K = 1024; off = 0;    rel = t; }
    else if (t < CUT2) { W = W1; bb = b1; K = 256;  off = 1024; rel = t - CUT1; }
    else if (t < CUT3) { W = W2; bb = b2; K = 64;   off = 1280; rel = t - CUT2; }
    else               { W = W3; bb = b3; K = 16;   off = 1344; rel = t - CUT3; }
    float acc = 0.f;
    const float* wr = W + (size_t)rel * K;
    for (int k = lane; k < K; k += 64) acc += b2f(pr[off + k]) * wr[k];
#pragma unroll
    for (int o2 = 1; o2 < 64; o2 <<= 1) acc += __shfl_xor(acc, o2);

    if (lane == 0) {
        c0 += cb[0]; c1 += cb[1]; c2 += cb[2];
        float tl = acc + bb[rel];
        float lseh = __logf(rs[row] + __expf(c0) + __expf(c1) + __expf(c2));
        float lp;
        if (t < CUT1) lp = tl - lseh;
        else {
            int c = (t < CUT2) ? 0 : (t < CUT3) ? 1 : 2;
            float cc = (c == 0) ? c0 : (c == 1) ? c1 : c2;
            lp = (cc - lseh) + (tl - __logf(rs[(c + 1) * 1024 + slot[row]]));
        }
        out[row] = -lp;
    }
}

// ======================= fallback path (round-1, verified) =======================
__global__ void cast_bf16_k(const float* __restrict__ in, u16* __restrict__ out, int n8) {
    int i = blockIdx.x * 256 + threadIdx.x;
    if (i >= n8) return;
    cast8(in, out, i);
}

__global__ void transpose_f_k(const float* __restrict__ in, float* __restrict__ out, int d, int rowOff) {
    __shared__ float tile[32][33];
    int tx = threadIdx.x, ty = threadIdx.y;
    int x = blockIdx.x * 32 + tx;
    int ybase = blockIdx.y * 32;
#pragma unroll
    for (int j = 0; j < 4; ++j) {
        int r = ty + j * 8;
        tile[r][tx] = (x < d) ? in[(size_t)(ybase + r) * d + x] : 0.f;
    }
    __syncthreads();
#pragma unroll
    for (int j = 0; j < 4; ++j) {
        int x2 = blockIdx.x * 32 + ty + j * 8;
        if (x2 < d) out[(size_t)(rowOff + x2) * 1024 + ybase + tx] = tile[tx][ty + j * 8];
    }
}

__global__ __launch_bounds__(256) void gemm_tn_k(
    const u16* __restrict__ A, int lda,
    const float* __restrict__ B, int ldb,
    const float* __restrict__ bias, int N, int K,
    u16* __restrict__ Cout, int ldc, float* __restrict__ rowsum)
{
    int tid = threadIdx.x;
    int wave = tid >> 6, lane = tid & 63;
    int l4 = lane & 15, quad = lane >> 4;
    int rbase = blockIdx.x * 16;
    int cbase = blockIdx.y * 256 + wave * 64;

    f4 acc[4] = {};
    v8s zero8 = {0, 0, 0, 0, 0, 0, 0, 0};
    const u16* arow = A + (size_t)(rbase + l4) * lda;
    int nk = (K + 31) >> 5;
    for (int kt = 0; kt < nk; ++kt) {
        int kk = (kt << 5) + quad * 8;
        v8s a = (kk < K) ? *(const v8s*)(arow + kk) : zero8;
#pragma unroll
        for (int t = 0; t < 4; ++t) {
            int col = cbase + t * 16 + l4;
            v8s b = zero8;
            if ((col < N) && (kk < K)) {
                const float* bp = B + (size_t)col * ldb + kk;
                float4 f0 = *(const float4*)bp;
                float4 f1 = *(const float4*)(bp + 4);
                union { uint4 u; v8s s; } bu;
                bu.u.x = pack2(f0.x, f0.y); bu.u.y = pack2(f0.z, f0.w);
                bu.u.z = pack2(f1.x, f1.y); bu.u.w = pack2(f1.z, f1.w);
                b = bu.s;
            }
            acc[t] = __builtin_amdgcn_mfma_f32_16x16x32_bf16(a, b, acc[t], 0, 0, 0);
        }
    }
    if (Cout) {
#pragma unroll
        for (int t = 0; t < 4; ++t) {
            int col = cbase + t * 16 + l4;
            if (col < N) {
#pragma unroll
                for (int r = 0; r < 4; ++r)
                    Cout[(size_t)(rbase + quad * 4 + r) * ldc + col] = f2b(acc[t][r]);
            }
        }
    } else {
        float part[4] = {0.f, 0.f, 0.f, 0.f};
#pragma unroll
        for (int t = 0; t < 4; ++t) {
            int col = cbase + t * 16 + l4;
            if (col < N) {
                float bb = bias[col];
#pragma unroll
                for (int r = 0; r < 4; ++r) part[r] += __expf(acc[t][r] + bb);
            }
        }
#pragma unroll
        for (int off = 1; off < 16; off <<= 1)
#pragma unroll
            for (int r = 0; r < 4; ++r) part[r] += __shfl_xor(part[r], off);
        if (l4 < 4) {
            float v = (l4 == 0) ? part[0] : (l4 == 1) ? part[1] : (l4 == 2) ? part[2] : part[3];
            atomicAdd(&rowsum[rbase + quad * 4 + l4], v);
        }
    }
}

__global__ __launch_bounds__(256) void gather_k(
    const u16* __restrict__ proj, const int* __restrict__ target,
    const float* __restrict__ cw, const float* __restrict__ cb,
    const float* __restrict__ W0, const float* __restrict__ b0,
    const float* __restrict__ W1, const float* __restrict__ b1,
    const float* __restrict__ W2, const float* __restrict__ b2,
    const float* __restrict__ W3, const float* __restrict__ b3,
    float* __restrict__ rs_head, float* __restrict__ cl, float* __restrict__ tl)
{
    int row = blockIdx.x * 4 + (threadIdx.x >> 6);
    int lane = threadIdx.x & 63;
    const u16* pr = proj + (size_t)row * LDP;

    float c0 = 0.f, c1 = 0.f, c2 = 0.f;
    for (int k = lane; k < 1024; k += 64) {
        float pv = b2f(pr[k]);
        c0 += pv * cw[k]; c1 += pv * cw[1024 + k]; c2 += pv * cw[2048 + k];
    }
#pragma unroll
    for (int off = 1; off < 64; off <<= 1) {
        c0 += __shfl_xor(c0, off); c1 += __shfl_xor(c1, off); c2 += __shfl_xor(c2, off);
    }
    int t = target[row];
    const float* W; const float* bb; int K, off, rel;
    if (t < CUT1)      { W = W0; bb = b0; K = 1024; off = 0;    rel = t; }
    else if (t < CUT2) { W = W1; bb = b1; K = 256;  off = 1024; rel = t - CUT1; }
    else if (t < CUT3) { W = W2; bb = b2; K = 64;   off = 1280; rel = t - CUT2; }
    else               { W = W3; bb = b3; K = 16;   off = 1344; rel = t - CUT3; }
    float acc = 0.f;
    const float* wr = W + (size_t)rel * K;
    for (int k = lane; k < K; k += 64) acc += b2f(pr[off + k]) * wr[k];
#pragma unroll
    for (int o2 = 1; o2 < 64; o2 <<= 1) acc += __shfl_xor(acc, o2);
    if (lane == 0) {
        c0 += cb[0]; c1 += cb[1]; c2 += cb[2];
        cl[row * 3 + 0] = c0; cl[row * 3 + 1] = c1; cl[row * 3 + 2] = c2;
        atomicAdd(&rs_head[row], __expf(c0) + __expf(c1) + __expf(c2));
        tl[row] = acc + bb[rel];
    }
}

__global__ void finalize_full_k(const int* __restrict__ target, const float* __restrict__ rs,
                                const float* __restrict__ cl, const float* __restrict__ tl,
                                float* __restrict__ out)
{
    int i = blockIdx.x * 256 + threadIdx.x;
    if (i >= NROWS) return;
    int t = target[i];
    float lseh = __logf(rs[i]);
    float lp;
    if (t < CUT1) lp = tl[i] - lseh;
    else {
        int c = (t < CUT2) ? 0 : (t < CUT3) ? 1 : 2;
        lp = (cl[i * 3 + c] - lseh) + (tl[i] - __logf(rs[(c + 1) * 1024 + i]));
    }
    out[i] = -lp;
}

// ======================= host =======================
extern "C" void kernel_launch(void* const* d_in, const int* in_sizes, int n_in,
                              void* d_out, int out_size, void* d_ws, size_t ws_size,
                              hipStream_t stream)
{
    const float* hidden = (const float*)d_in[0];
    const int*   target = (const int*)d_in[1];
    const float* W0 = (const float*)d_in[2];
    const float* b0 = (const float*)d_in[3];
    const float* p0 = (const float*)d_in[4];
    const float* W1 = (const float*)d_in[5];
    const float* b1 = (const float*)d_in[6];
    const float* p1 = (const float*)d_in[7];
    const float* W2 = (const float*)d_in[8];
    const float* b2 = (const float*)d_in[9];
    const float* p2 = (const float*)d_in[10];
    const float* W3 = (const float*)d_in[11];
    const float* b3 = (const float*)d_in[12];
    const float* p3 = (const float*)d_in[13];
    const float* cw = (const float*)d_in[14];
    const float* cb = (const float*)d_in[15];
    float* out = (float*)d_out;
    char* w = (char*)d_ws;

    if (ws_size >= 84000000ull) {
        // ---- fast path ----
        u16*   hb   = (u16*)(w + 0);             // 1024x1024 bf16
        u16*   pTb  = (u16*)(w + 2097152);       // [1360][1024] bf16
        u16*   proj = (u16*)(w + 4882432);       // [1024][1360] bf16
        u16*   W0b  = (u16*)(w + 7667712);       // 19997x1024
        u16*   W1b  = (u16*)(w + 48621568);      // 20000x256
        u16*   W2b  = (u16*)(w + 58861568);      // 160000x64
        u16*   W3b  = (u16*)(w + 79341568);      // 67738x32 (zero-padded k16..31)
        float* rs   = (float*)(w + 83676800);    // 4x1024
        int*   cnt  = (int*)(w + 83693184);      // 3 (+pad)
        int*   slot = (int*)(w + 83693200);      // 1024
        int*   rmap = (int*)(w + 83697296);      // 3x1024

        prep_k<<<PREP_CAST_BLKS + PREP_TR_BLKS + 1, 256, 0, stream>>>(
            hidden, W0, W1, W2, W3, p0, p1, p2, p3, target,
            hb, W0b, W1b, W2b, W3b, pTb, rs, cnt, slot, rmap);

        proj_gemm_k<<<88, 256, 0, stream>>>(hb, pTb, proj);

        sumexp_k<<<SE_GRID, 256, 0, stream>>>(proj, W0b, W1b, W2b, W3b,
                                              b0, b1, b2, b3, rs, rmap, cnt);

        final_k<<<256, 256, 0, stream>>>(proj, target, slot, cw, cb,
                                         W0, b0, W1, b1, W2, b2, W3, b3, rs, out);
    } else {
        // ---- round-1 verified fallback ----
        float* pT   = (float*)w;                          // [1360][1024] f32
        u16*   hb   = (u16*)(w + 5570560);                // [1024][1024] bf16
        u16*   proj = (u16*)(w + 7667712);                // [1024][1360] bf16
        float* rs   = (float*)(w + 10452992);
        float* cl   = (float*)(w + 10469376);
        float* tl   = (float*)(w + 10481664);
        dim3 tb(32, 8);

        hipMemsetAsync(rs, 0, 4 * 1024 * sizeof(float), stream);
        cast_bf16_k<<<512, 256, 0, stream>>>(hidden, hb, 131072);
        transpose_f_k<<<dim3(32, 32), tb, 0, stream>>>(p0, pT, 1024, 0);
        transpose_f_k<<<dim3(8, 32),  tb, 0, stream>>>(p1, pT, 256, 1024);
        transpose_f_k<<<dim3(2, 32),  tb, 0, stream>>>(p2, pT, 64, 1280);
        transpose_f_k<<<dim3(1, 32),  tb, 0, stream>>>(p3, pT, 16, 1344);

        gemm_tn_k<<<dim3(64, 6), 256, 0, stream>>>(hb, 1024, pT, 1024, nullptr,
                                                   1360, 1024, proj, LDP, nullptr);
        gemm_tn_k<<<dim3(64, 79), 256, 0, stream>>>(proj, LDP, W0, 1024, b0,
                                                    CUT1, 1024, nullptr, 0, rs);
        gemm_tn_k<<<dim3(64, 79), 256, 0, stream>>>(proj + 1024, LDP, W1, 256, b1,
                                                    20000, 256, nullptr, 0, rs + 1024);
        gemm_tn_k<<<dim3(64, 625), 256, 0, stream>>>(proj + 1280, LDP, W2, 64, b2,
                                                     160000, 64, nullptr, 0, rs + 2048);
        gemm_tn_k<<<dim3(64, 265), 256, 0, stream>>>(proj + 1344, LDP, W3, 16, b3,
                                                     67738, 16, nullptr, 0, rs + 3072);

        gather_k<<<256, 256, 0, stream>>>(proj, target, cw, cb,
                                          W0, b0, W1, b1, W2, b2, W3, b3, rs, cl, tl);
        finalize_full_k<<<4, 256, 0, stream>>>(target, rs, cl, tl, out);
    }
}

// Round 5
// 433.868 us; speedup vs baseline: 1.1920x; 1.0215x over previous
//
#include <hip/hip_runtime.h>
#include <stdint.h>

typedef short v8s __attribute__((ext_vector_type(8)));
typedef float f4 __attribute__((ext_vector_type(4)));
typedef unsigned short u16;
typedef unsigned int u32;

#define CUT1 19997
#define CUT2 39997
#define CUT3 199997
#define NROWS 1024
#define LDP 1360   // packed proj cols: 1024 + 256 + 64 + 16

__device__ __forceinline__ u32 pack2(float a, float b) {
    return (__float_as_uint(a) >> 16) | (__float_as_uint(b) & 0xffff0000u);
}
__device__ __forceinline__ float b2f(u16 h) { return __uint_as_float(((u32)h) << 16); }
__device__ __forceinline__ u16 f2b(float f) { return (u16)(__float_as_uint(f) >> 16); }

__device__ __forceinline__ void gload16(const void* g, void* l) {
    __builtin_amdgcn_global_load_lds(
        (const __attribute__((address_space(1))) u32*)g,
        (__attribute__((address_space(3))) u32*)l, 16, 0, 0);
}

__device__ __forceinline__ void cast8(const float* __restrict__ in, u16* __restrict__ out, size_t j) {
    const float4* p = (const float4*)(in + j * 8);
    float4 a = p[0], b = p[1];
    uint4 o = { pack2(a.x, a.y), pack2(a.z, a.w), pack2(b.x, b.y), pack2(b.z, b.w) };
    *(uint4*)(out + j * 8) = o;
}

// ======================= small prep: hidden cast + p transpose + classify =======================
__global__ __launch_bounds__(256) void prep_small_k(
    const float* __restrict__ hidden,
    const float* __restrict__ p0, const float* __restrict__ p1,
    const float* __restrict__ p2, const float* __restrict__ p3,
    const int* __restrict__ target,
    u16* __restrict__ hb, u16* __restrict__ pTb,
    float* __restrict__ rs, int* __restrict__ cnt, int* __restrict__ slot,
    int* __restrict__ rowmap)
{
    int bid = blockIdx.x;
    int tid = threadIdx.x;

    if (bid < 512) {                       // hidden cast: 131072 groups of 8
        cast8(hidden, hb, bid * 256 + tid);
        return;
    }
    if (bid < 1888) {                      // p transpose -> bf16 [1360][1024]
        int b = bid - 512;
        const float* src; int d, rowOff, bx, by;
        if (b < 1024)      { src = p0; d = 1024; rowOff = 0;    bx = b & 31;          by = b >> 5; }
        else if (b < 1280) { src = p1; d = 256;  rowOff = 1024; bx = (b - 1024) & 7;  by = (b - 1024) >> 3; }
        else if (b < 1344) { src = p2; d = 64;   rowOff = 1280; bx = (b - 1280) & 1;  by = (b - 1280) >> 1; }
        else               { src = p3; d = 16;   rowOff = 1344; bx = 0;               by = b - 1344; }
        __shared__ float tile[32][33];
        int tx = tid & 31, ty = tid >> 5;
        int x = bx * 32 + tx;
        int ybase = by * 32;
#pragma unroll
        for (int j = 0; j < 4; ++j) {
            int r = ty + j * 8;
            tile[r][tx] = (x < d) ? src[(size_t)(ybase + r) * d + x] : 0.f;
        }
        __syncthreads();
#pragma unroll
        for (int j = 0; j < 4; ++j) {
            int x2 = bx * 32 + ty + j * 8;
            if (x2 < d) pTb[(size_t)(rowOff + x2) * 1024 + ybase + tx] = f2b(tile[tx][ty + j * 8]);
        }
        return;
    }

    // ---- classify block: zero rs + rowmap, bucket targets ----
    __shared__ int lcnt[3];
    for (int i = tid; i < 4096; i += 256) rs[i] = 0.f;
    for (int i = tid; i < 3072; i += 256) rowmap[i] = 0;
    if (tid < 3) lcnt[tid] = 0;
    __syncthreads();
    for (int r = tid; r < NROWS; r += 256) {
        int t = target[r];
        int c = (t < CUT1) ? -1 : (t < CUT2) ? 0 : (t < CUT3) ? 1 : 2;
        int s = -1;
        if (c >= 0) {
            s = atomicAdd(&lcnt[c], 1);
            rowmap[c * 1024 + s] = r;
        }
        slot[r] = s;
    }
    __syncthreads();
    if (tid < 3) cnt[tid] = lcnt[tid];
}

// ======================= MFMA GEMM body, BK=32, seg-major conflict-free LDS =======================
// TN: C[m][n] = sum_k A_bf16[m][k] * B_bf16[n][k]; BM=128; 4 waves 2x2 (64x64 each).
// Block covers NCOL col-tiles of 128 serially (reuses staging regs; one epilogue).
// MODE 0: store bf16 C (NCOL=1 only). MODE 1: rowsum[m] += sum_n exp(C[m][n]+bias[n]).
template<int MODE, int NCOL>
__device__ __forceinline__ void gemm_body(
    u16* __restrict__ As, u16* __restrict__ Bs,
    const u16* __restrict__ A, int lda, const int* __restrict__ rowmap,
    const u16* __restrict__ B, int ldb,
    const float* __restrict__ bias, int N, int K,
    u16* __restrict__ Cout, int ldc,
    float* __restrict__ rowsum, const int* __restrict__ count,
    int bx, int byg)
{
    const int tid = threadIdx.x;
    const int rbase = bx * 128;
    if (MODE == 1 && count) {
        int c = *count;
        if (rbase >= ((c + 127) & ~127)) return;
    }

    const int wave = tid >> 6, lane = tid & 63;
    const int l4 = lane & 15, quad = lane >> 4;
    const int wg = (wave >> 1) * 4;   // A row16-group base
    const int cg = (wave & 1) * 4;    // B col16-group base

    // staging slot indices: {tid, 256+tid}
    const int g0 = tid >> 6, seg0 = (tid >> 4) & 3, r0 = tid & 15;
    const int s1 = 256 + tid;
    const int g1 = s1 >> 6, seg1 = (s1 >> 4) & 3, r1 = s1 & 15;

    const u16 *Asrc0, *Asrc1;
    {
        int ar0 = rbase + g0 * 16 + r0, ar1 = rbase + g1 * 16 + r1;
        if (rowmap) { ar0 = rowmap[ar0]; ar1 = rowmap[ar1]; }
        Asrc0 = A + (size_t)ar0 * lda + seg0 * 8;
        Asrc1 = A + (size_t)ar1 * lda + seg1 * 8;
    }
    u16* Ad0 = &As[tid * 8]; u16* Ad1 = &As[(256 + tid) * 8];
    u16* Bd0 = &Bs[tid * 8]; u16* Bd1 = &Bs[(256 + tid) * 8];

    float part[4][4];
    if (MODE == 1) {
#pragma unroll
        for (int r = 0; r < 4; ++r)
#pragma unroll
            for (int g = 0; g < 4; ++g) part[r][g] = 0.f;
    }

    const int wr = wg * 16, wc = cg * 16;

    for (int ct = 0; ct < NCOL; ++ct) {
        const int cbase = (byg * NCOL + ct) * 128;
        int bc0 = cbase + g0 * 16 + r0; if (bc0 >= N) bc0 = N - 1;
        int bc1 = cbase + g1 * 16 + r1; if (bc1 >= N) bc1 = N - 1;
        const u16* Bsrc0 = B + (size_t)bc0 * ldb + seg0 * 8;
        const u16* Bsrc1 = B + (size_t)bc1 * ldb + seg1 * 8;

        f4 acc[4][4] = {};
        for (int kk = 0; kk < K; kk += 32) {
            gload16(Asrc0 + kk, Ad0);
            gload16(Asrc1 + kk, Ad1);
            gload16(Bsrc0 + kk, Bd0);
            gload16(Bsrc1 + kk, Bd1);
            __syncthreads();
            v8s af[4], bf[4];
#pragma unroll
            for (int r = 0; r < 4; ++r)
                af[r] = *(const v8s*)&As[((wg + r) * 64 + quad * 16 + l4) * 8];
#pragma unroll
            for (int c = 0; c < 4; ++c)
                bf[c] = *(const v8s*)&Bs[((cg + c) * 64 + quad * 16 + l4) * 8];
#pragma unroll
            for (int r = 0; r < 4; ++r)
#pragma unroll
                for (int c = 0; c < 4; ++c)
                    acc[r][c] = __builtin_amdgcn_mfma_f32_16x16x32_bf16(af[r], bf[c], acc[r][c], 0, 0, 0);
            __syncthreads();
        }

        if (MODE == 0) {
#pragma unroll
            for (int c = 0; c < 4; ++c) {
                int col = cbase + wc + c * 16 + l4;
                if (col < N) {
#pragma unroll
                    for (int r = 0; r < 4; ++r)
#pragma unroll
                        for (int g = 0; g < 4; ++g) {
                            int row = rbase + wr + r * 16 + quad * 4 + g;
                            Cout[(size_t)row * ldc + col] = f2b(acc[r][c][g]);
                        }
                }
            }
        } else {
#pragma unroll
            for (int c = 0; c < 4; ++c) {
                int col = cbase + wc + c * 16 + l4;
                if (col < N) {
                    float bb = bias[col];
#pragma unroll
                    for (int r = 0; r < 4; ++r)
#pragma unroll
                        for (int g = 0; g < 4; ++g)
                            part[r][g] += __expf(acc[r][c][g] + bb);
                }
            }
        }
    }

    if (MODE == 1) {
#pragma unroll
        for (int off = 1; off < 16; off <<= 1)
#pragma unroll
            for (int r = 0; r < 4; ++r)
#pragma unroll
                for (int g = 0; g < 4; ++g)
                    part[r][g] += __shfl_xor(part[r][g], off);
        float v = part[0][0];
#pragma unroll
        for (int r = 0; r < 4; ++r)
#pragma unroll
            for (int g = 0; g < 4; ++g)
                if (l4 == r * 4 + g) v = part[r][g];
        int row = rbase + wr + (l4 >> 2) * 16 + quad * 4 + (l4 & 3);
        atomicAdd(&rowsum[row], v);
    }
}

// ======================= fused W-cast + proj GEMM =======================
// blocks [0,88): proj = hidden @ [p0|p1|p2|p3]; [88,17852): W0..W3 fp32->bf16 casts
#define CP_E0 2559616
#define CP_E1 3199616
#define CP_E2 4479616
__global__ __launch_bounds__(256) void castproj_k(
    const u16* __restrict__ hb, const u16* __restrict__ pTb, u16* __restrict__ proj,
    const float* __restrict__ W0, const float* __restrict__ W1,
    const float* __restrict__ W2, const float* __restrict__ W3,
    u16* __restrict__ W0b, u16* __restrict__ W1b,
    u16* __restrict__ W2b, u16* __restrict__ W3b)
{
    __shared__ __align__(16) u16 As[4096];
    __shared__ __align__(16) u16 Bs[4096];
    int bid = blockIdx.x;
    if (bid < 88) {
        gemm_body<0, 1>(As, Bs, hb, 1024, nullptr, pTb, 1024, nullptr, 1360, 1024,
                        proj, LDP, nullptr, nullptr, bid & 7, bid >> 3);
        return;
    }
    int i = (bid - 88) * 256 + threadIdx.x;
    if (i < CP_E0) { cast8(W0, W0b, i); return; }
    if (i < CP_E1) { cast8(W1, W1b, i - CP_E0); return; }
    if (i < CP_E2) { cast8(W2, W2b, i - CP_E1); return; }
    int r = i - CP_E2;
    if (r >= 67738) return;
    // W3 [67738][16] -> bf16 padded to ld=32
    const float4* p = (const float4*)(W3 + (size_t)r * 16);
    float4 a = p[0], b = p[1], c = p[2], d = p[3];
    uint4 o0 = { pack2(a.x, a.y), pack2(a.z, a.w), pack2(b.x, b.y), pack2(b.z, b.w) };
    uint4 o1 = { pack2(c.x, c.y), pack2(c.z, c.w), pack2(d.x, d.y), pack2(d.z, d.w) };
    uint4 z = { 0, 0, 0, 0 };
    uint4* q = (uint4*)(W3b + (size_t)r * 32);
    q[0] = o0; q[1] = o1; q[2] = z; q[3] = z;
}

// ======================= fused sumexp: head + 3 tails (multi-col tail blocks) =======================
// regions: [0,1256) head NCOL=1; [1256,1576) t1 NCOL=4; [1576,2832) t2 NCOL=8; [2832,3368) t3 NCOL=8
#define SE_GRID 3368
__global__ __launch_bounds__(256) void sumexp_k(
    const u16* __restrict__ proj,
    const u16* __restrict__ W0b, const u16* __restrict__ W1b,
    const u16* __restrict__ W2b, const u16* __restrict__ W3b,
    const float* __restrict__ b0, const float* __restrict__ b1,
    const float* __restrict__ b2, const float* __restrict__ b3,
    float* __restrict__ rs, const int* __restrict__ rmap, const int* __restrict__ cnt)
{
    __shared__ __align__(16) u16 As[4096];
    __shared__ __align__(16) u16 Bs[4096];
    int bid = blockIdx.x;
    if (bid < 1256) {
        gemm_body<1, 1>(As, Bs, proj, LDP, nullptr, W0b, 1024, b0, CUT1, 1024,
                        nullptr, 0, rs, nullptr, bid & 7, bid >> 3);
    } else if (bid < 1576) {
        int rel = bid - 1256;
        gemm_body<1, 4>(As, Bs, proj + 1024, LDP, rmap, W1b, 256, b1, 20000, 256,
                        nullptr, 0, rs + 1024, cnt + 0, rel & 7, rel >> 3);
    } else if (bid < 2832) {
        int rel = bid - 1576;
        gemm_body<1, 8>(As, Bs, proj + 1280, LDP, rmap + 1024, W2b, 64, b2, 160000, 64,
                        nullptr, 0, rs + 2048, cnt + 1, rel & 7, rel >> 3);
    } else {
        int rel = bid - 2832;
        gemm_body<1, 8>(As, Bs, proj + 1344, LDP, rmap + 2048, W3b, 32, b3, 67738, 32,
                        nullptr, 0, rs + 3072, cnt + 2, rel & 7, rel >> 3);
    }
}

// ======================= fused gather + finalize =======================
__global__ __launch_bounds__(256) void final_k(
    const u16* __restrict__ proj, const int* __restrict__ target, const int* __restrict__ slot,
    const float* __restrict__ cw, const float* __restrict__ cb,
    const float* __restrict__ W0, const float* __restrict__ b0,
    const float* __restrict__ W1, const float* __restrict__ b1,
    const float* __restrict__ W2, const float* __restrict__ b2,
    const float* __restrict__ W3, const float* __restrict__ b3,
    const float* __restrict__ rs, float* __restrict__ out)
{
    int row = blockIdx.x * 4 + (threadIdx.x >> 6);
    int lane = threadIdx.x & 63;
    const u16* pr = proj + (size_t)row * LDP;

    float c0 = 0.f, c1 = 0.f, c2 = 0.f;
    for (int k = lane; k < 1024; k += 64) {
        float pv = b2f(pr[k]);
        c0 += pv * cw[k]; c1 += pv * cw[1024 + k]; c2 += pv * cw[2048 + k];
    }
#pragma unroll
    for (int off = 1; off < 64; off <<= 1) {
        c0 += __shfl_xor(c0, off); c1 += __shfl_xor(c1, off); c2 += __shfl_xor(c2, off);
    }

    int t = target[row];
    const float* W; const float* bb; int K, off, rel;
    if (t < CUT1)      { W = W0; bb = b0; K = 1024; off = 0;    rel = t; }
    else if (t < CUT2) { W = W1; bb = b1; K = 256;  off = 1024; rel = t - CUT1; }
    else if (t < CUT3) { W = W2; bb = b2; K = 64;   off = 1280; rel = t - CUT2; }
    else               { W = W3; bb = b3; K = 16;   off = 1344; rel = t - CUT3; }
    float acc = 0.f;
    const float* wr = W + (size_t)rel * K;
    for (int k = lane; k < K; k += 64) acc += b2f(pr[off + k]) * wr[k];
#pragma unroll
    for (int o2 = 1; o2 < 64; o2 <<= 1) acc += __shfl_xor(acc, o2);

    if (lane == 0) {
        c0 += cb[0]; c1 += cb[1]; c2 += cb[2];
        float tl = acc + bb[rel];
        float lseh = __logf(rs[row] + __expf(c0) + __expf(c1) + __expf(c2));
        float lp;
        if (t < CUT1) lp = tl - lseh;
        else {
            int c = (t < CUT2) ? 0 : (t < CUT3) ? 1 : 2;
            float cc = (c == 0) ? c0 : (c == 1) ? c1 : c2;
            lp = (cc - lseh) + (tl - __logf(rs[(c + 1) * 1024 + slot[row]]));
        }
        out[row] = -lp;
    }
}

// ======================= fallback path (round-1, verified) =======================
__global__ void cast_bf16_k(const float* __restrict__ in, u16* __restrict__ out, int n8) {
    int i = blockIdx.x * 256 + threadIdx.x;
    if (i >= n8) return;
    cast8(in, out, i);
}

__global__ void transpose_f_k(const float* __restrict__ in, float* __restrict__ out, int d, int rowOff) {
    __shared__ float tile[32][33];
    int tx = threadIdx.x, ty = threadIdx.y;
    int x = blockIdx.x * 32 + tx;
    int ybase = blockIdx.y * 32;
#pragma unroll
    for (int j = 0; j < 4; ++j) {
        int r = ty + j * 8;
        tile[r][tx] = (x < d) ? in[(size_t)(ybase + r) * d + x] : 0.f;
    }
    __syncthreads();
#pragma unroll
    for (int j = 0; j < 4; ++j) {
        int x2 = blockIdx.x * 32 + ty + j * 8;
        if (x2 < d) out[(size_t)(rowOff + x2) * 1024 + ybase + tx] = tile[tx][ty + j * 8];
    }
}

__global__ __launch_bounds__(256) void gemm_tn_k(
    const u16* __restrict__ A, int lda,
    const float* __restrict__ B, int ldb,
    const float* __restrict__ bias, int N, int K,
    u16* __restrict__ Cout, int ldc, float* __restrict__ rowsum)
{
    int tid = threadIdx.x;
    int wave = tid >> 6, lane = tid & 63;
    int l4 = lane & 15, quad = lane >> 4;
    int rbase = blockIdx.x * 16;
    int cbase = blockIdx.y * 256 + wave * 64;

    f4 acc[4] = {};
    v8s zero8 = {0, 0, 0, 0, 0, 0, 0, 0};
    const u16* arow = A + (size_t)(rbase + l4) * lda;
    int nk = (K + 31) >> 5;
    for (int kt = 0; kt < nk; ++kt) {
        int kk = (kt << 5) + quad * 8;
        v8s a = (kk < K) ? *(const v8s*)(arow + kk) : zero8;
#pragma unroll
        for (int t = 0; t < 4; ++t) {
            int col = cbase + t * 16 + l4;
            v8s b = zero8;
            if ((col < N) && (kk < K)) {
                const float* bp = B + (size_t)col * ldb + kk;
                float4 f0 = *(const float4*)bp;
                float4 f1 = *(const float4*)(bp + 4);
                union { uint4 u; v8s s; } bu;
                bu.u.x = pack2(f0.x, f0.y); bu.u.y = pack2(f0.z, f0.w);
                bu.u.z = pack2(f1.x, f1.y); bu.u.w = pack2(f1.z, f1.w);
                b = bu.s;
            }
            acc[t] = __builtin_amdgcn_mfma_f32_16x16x32_bf16(a, b, acc[t], 0, 0, 0);
        }
    }
    if (Cout) {
#pragma unroll
        for (int t = 0; t < 4; ++t) {
            int col = cbase + t * 16 + l4;
            if (col < N) {
#pragma unroll
                for (int r = 0; r < 4; ++r)
                    Cout[(size_t)(rbase + quad * 4 + r) * ldc + col] = f2b(acc[t][r]);
            }
        }
    } else {
        float part[4] = {0.f, 0.f, 0.f, 0.f};
#pragma unroll
        for (int t = 0; t < 4; ++t) {
            int col = cbase + t * 16 + l4;
            if (col < N) {
                float bb = bias[col];
#pragma unroll
                for (int r = 0; r < 4; ++r) part[r] += __expf(acc[t][r] + bb);
            }
        }
#pragma unroll
        for (int off = 1; off < 16; off <<= 1)
#pragma unroll
            for (int r = 0; r < 4; ++r) part[r] += __shfl_xor(part[r], off);
        if (l4 < 4) {
            float v = (l4 == 0) ? part[0] : (l4 == 1) ? part[1] : (l4 == 2) ? part[2] : part[3];
            atomicAdd(&rowsum[rbase + quad * 4 + l4], v);
        }
    }
}

__global__ __launch_bounds__(256) void gather_k(
    const u16* __restrict__ proj, const int* __restrict__ target,
    const float* __restrict__ cw, const float* __restrict__ cb,
    const float* __restrict__ W0, const float* __restrict__ b0,
    const float* __restrict__ W1, const float* __restrict__ b1,
    const float* __restrict__ W2, const float* __restrict__ b2,
    const float* __restrict__ W3, const float* __restrict__ b3,
    float* __restrict__ rs_head, float* __restrict__ cl, float* __restrict__ tl)
{
    int row = blockIdx.x * 4 + (threadIdx.x >> 6);
    int lane = threadIdx.x & 63;
    const u16* pr = proj + (size_t)row * LDP;

    float c0 = 0.f, c1 = 0.f, c2 = 0.f;
    for (int k = lane; k < 1024; k += 64) {
        float pv = b2f(pr[k]);
        c0 += pv * cw[k]; c1 += pv * cw[1024 + k]; c2 += pv * cw[2048 + k];
    }
#pragma unroll
    for (int off = 1; off < 64; off <<= 1) {
        c0 += __shfl_xor(c0, off); c1 += __shfl_xor(c1, off); c2 += __shfl_xor(c2, off);
    }
    int t = target[row];
    const float* W; const float* bb; int K, off, rel;
    if (t < CUT1)      { W = W0; bb = b0; K = 1024; off = 0;    rel = t; }
    else if (t < CUT2) { W = W1; bb = b1; K = 256;  off = 1024; rel = t - CUT1; }
    else if (t < CUT3) { W = W2; bb = b2; K = 64;   off = 1280; rel = t - CUT2; }
    else               { W = W3; bb = b3; K = 16;   off = 1344; rel = t - CUT3; }
    float acc = 0.f;
    const float* wr = W + (size_t)rel * K;
    for (int k = lane; k < K; k += 64) acc += b2f(pr[off + k]) * wr[k];
#pragma unroll
    for (int o2 = 1; o2 < 64; o2 <<= 1) acc += __shfl_xor(acc, o2);
    if (lane == 0) {
        c0 += cb[0]; c1 += cb[1]; c2 += cb[2];
        cl[row * 3 + 0] = c0; cl[row * 3 + 1] = c1; cl[row * 3 + 2] = c2;
        atomicAdd(&rs_head[row], __expf(c0) + __expf(c1) + __expf(c2));
        tl[row] = acc + bb[rel];
    }
}

__global__ void finalize_full_k(const int* __restrict__ target, const float* __restrict__ rs,
                                const float* __restrict__ cl, const float* __restrict__ tl,
                                float* __restrict__ out)
{
    int i = blockIdx.x * 256 + threadIdx.x;
    if (i >= NROWS) return;
    int t = target[i];
    float lseh = __logf(rs[i]);
    float lp;
    if (t < CUT1) lp = tl[i] - lseh;
    else {
        int c = (t < CUT2) ? 0 : (t < CUT3) ? 1 : 2;
        lp = (cl[i * 3 + c] - lseh) + (tl[i] - __logf(rs[(c + 1) * 1024 + i]));
    }
    out[i] = -lp;
}

// ======================= host =======================
extern "C" void kernel_launch(void* const* d_in, const int* in_sizes, int n_in,
                              void* d_out, int out_size, void* d_ws, size_t ws_size,
                              hipStream_t stream)
{
    const float* hidden = (const float*)d_in[0];
    const int*   target = (const int*)d_in[1];
    const float* W0 = (const float*)d_in[2];
    const float* b0 = (const float*)d_in[3];
    const float* p0 = (const float*)d_in[4];
    const float* W1 = (const float*)d_in[5];
    const float* b1 = (const float*)d_in[6];
    const float* p1 = (const float*)d_in[7];
    const float* W2 = (const float*)d_in[8];
    const float* b2 = (const float*)d_in[9];
    const float* p2 = (const float*)d_in[10];
    const float* W3 = (const float*)d_in[11];
    const float* b3 = (const float*)d_in[12];
    const float* p3 = (const float*)d_in[13];
    const float* cw = (const float*)d_in[14];
    const float* cb = (const float*)d_in[15];
    float* out = (float*)d_out;
    char* w = (char*)d_ws;

    if (ws_size >= 84000000ull) {
        // ---- fast path ----
        u16*   hb   = (u16*)(w + 0);             // 1024x1024 bf16
        u16*   pTb  = (u16*)(w + 2097152);       // [1360][1024] bf16
        u16*   proj = (u16*)(w + 4882432);       // [1024][1360] bf16
        u16*   W0b  = (u16*)(w + 7667712);       // 19997x1024
        u16*   W1b  = (u16*)(w + 48621568);      // 20000x256
        u16*   W2b  = (u16*)(w + 58861568);      // 160000x64
        u16*   W3b  = (u16*)(w + 79341568);      // 67738x32 (zero-padded k16..31)
        float* rs   = (float*)(w + 83676800);    // 4x1024
        int*   cnt  = (int*)(w + 83693184);      // 3 (+pad)
        int*   slot = (int*)(w + 83693200);      // 1024
        int*   rmap = (int*)(w + 83697296);      // 3x1024

        prep_small_k<<<1889, 256, 0, stream>>>(hidden, p0, p1, p2, p3, target,
                                               hb, pTb, rs, cnt, slot, rmap);

        castproj_k<<<17852, 256, 0, stream>>>(hb, pTb, proj,
                                              W0, W1, W2, W3, W0b, W1b, W2b, W3b);

        sumexp_k<<<SE_GRID, 256, 0, stream>>>(proj, W0b, W1b, W2b, W3b,
                                              b0, b1, b2, b3, rs, rmap, cnt);

        final_k<<<256, 256, 0, stream>>>(proj, target, slot, cw, cb,
                                         W0, b0, W1, b1, W2, b2, W3, b3, rs, out);
    } else {
        // ---- round-1 verified fallback ----
        float* pT   = (float*)w;                          // [1360][1024] f32
        u16*   hb   = (u16*)(w + 5570560);                // [1024][1024] bf16
        u16*   proj = (u16*)(w + 7667712);                // [1024][1360] bf16
        float* rs   = (float*)(w + 10452992);
        float* cl   = (float*)(w + 10469376);
        float* tl   = (float*)(w + 10481664);
        dim3 tb(32, 8);

        hipMemsetAsync(rs, 0, 4 * 1024 * sizeof(float), stream);
        cast_bf16_k<<<512, 256, 0, stream>>>(hidden, hb, 131072);
        transpose_f_k<<<dim3(32, 32), tb, 0, stream>>>(p0, pT, 1024, 0);
        transpose_f_k<<<dim3(8, 32),  tb, 0, stream>>>(p1, pT, 256, 1024);
        transpose_f_k<<<dim3(2, 32),  tb, 0, stream>>>(p2, pT, 64, 1280);
        transpose_f_k<<<dim3(1, 32),  tb, 0, stream>>>(p3, pT, 16, 1344);

        gemm_tn_k<<<dim3(64, 6), 256, 0, stream>>>(hb, 1024, pT, 1024, nullptr,
                                                   1360, 1024, proj, LDP, nullptr);
        gemm_tn_k<<<dim3(64, 79), 256, 0, stream>>>(proj, LDP, W0, 1024, b0,
                                                    CUT1, 1024, nullptr, 0, rs);
        gemm_tn_k<<<dim3(64, 79), 256, 0, stream>>>(proj + 1024, LDP, W1, 256, b1,
                                                    20000, 256, nullptr, 0, rs + 1024);
        gemm_tn_k<<<dim3(64, 625), 256, 0, stream>>>(proj + 1280, LDP, W2, 64, b2,
                                                     160000, 64, nullptr, 0, rs + 2048);
        gemm_tn_k<<<dim3(64, 265), 256, 0, stream>>>(proj + 1344, LDP, W3, 16, b3,
                                                     67738, 16, nullptr, 0, rs + 3072);

        gather_k<<<256, 256, 0, stream>>>(proj, target, cw, cb,
                                          W0, b0, W1, b1, W2, b2, W3, b3, rs, cl, tl);
        finalize_full_k<<<4, 256, 0, stream>>>(target, rs, cl, tl, out);
    }
}

// Round 6
// 431.707 us; speedup vs baseline: 1.1979x; 1.0050x over previous
//
#include <hip/hip_runtime.h>
#include <stdint.h>

typedef short v8s __attribute__((ext_vector_type(8)));
typedef float f4 __attribute__((ext_vector_type(4)));
typedef unsigned short u16;
typedef unsigned int u32;

#define CUT1 19997
#define CUT2 39997
#define CUT3 199997
#define NROWS 1024
#define LDP 1360   // packed proj cols: 1024 + 256 + 64 + 16

#define NG_HEAD 157
#define NG_T1 40
#define NG_T2 157
#define NG_T3 67

__device__ __forceinline__ u32 pack2(float a, float b) {
    return (__float_as_uint(a) >> 16) | (__float_as_uint(b) & 0xffff0000u);
}
__device__ __forceinline__ float b2f(u16 h) { return __uint_as_float(((u32)h) << 16); }
__device__ __forceinline__ u16 f2b(float f) { return (u16)(__float_as_uint(f) >> 16); }

__device__ __forceinline__ void gload16(const void* g, void* l) {
    __builtin_amdgcn_global_load_lds(
        (const __attribute__((address_space(1))) u32*)g,
        (__attribute__((address_space(3))) u32*)l, 16, 0, 0);
}

__device__ __forceinline__ void cast8(const float* __restrict__ in, u16* __restrict__ out, size_t j) {
    const float4* p = (const float4*)(in + j * 8);
    float4 a = p[0], b = p[1];
    uint4 o = { pack2(a.x, a.y), pack2(a.z, a.w), pack2(b.x, b.y), pack2(b.z, b.w) };
    *(uint4*)(out + j * 8) = o;
}

// ======================= small prep: hidden cast + p transpose + classify =======================
__global__ __launch_bounds__(256) void prep_small_k(
    const float* __restrict__ hidden,
    const float* __restrict__ p0, const float* __restrict__ p1,
    const float* __restrict__ p2, const float* __restrict__ p3,
    const int* __restrict__ target,
    u16* __restrict__ hb, u16* __restrict__ pTb,
    int* __restrict__ cnt, int* __restrict__ slot,
    int* __restrict__ rowmap)
{
    int bid = blockIdx.x;
    int tid = threadIdx.x;

    if (bid < 512) {                       // hidden cast: 131072 groups of 8
        cast8(hidden, hb, bid * 256 + tid);
        return;
    }
    if (bid < 1888) {                      // p transpose -> bf16 [1360][1024]
        int b = bid - 512;
        const float* src; int d, rowOff, bx, by;
        if (b < 1024)      { src = p0; d = 1024; rowOff = 0;    bx = b & 31;          by = b >> 5; }
        else if (b < 1280) { src = p1; d = 256;  rowOff = 1024; bx = (b - 1024) & 7;  by = (b - 1024) >> 3; }
        else if (b < 1344) { src = p2; d = 64;   rowOff = 1280; bx = (b - 1280) & 1;  by = (b - 1280) >> 1; }
        else               { src = p3; d = 16;   rowOff = 1344; bx = 0;               by = b - 1344; }
        __shared__ float tile[32][33];
        int tx = tid & 31, ty = tid >> 5;
        int x = bx * 32 + tx;
        int ybase = by * 32;
#pragma unroll
        for (int j = 0; j < 4; ++j) {
            int r = ty + j * 8;
            tile[r][tx] = (x < d) ? src[(size_t)(ybase + r) * d + x] : 0.f;
        }
        __syncthreads();
#pragma unroll
        for (int j = 0; j < 4; ++j) {
            int x2 = bx * 32 + ty + j * 8;
            if (x2 < d) pTb[(size_t)(rowOff + x2) * 1024 + ybase + tx] = f2b(tile[tx][ty + j * 8]);
        }
        return;
    }

    // ---- classify block: zero rowmap, bucket targets ----
    __shared__ int lcnt[3];
    for (int i = tid; i < 3072; i += 256) rowmap[i] = 0;
    if (tid < 3) lcnt[tid] = 0;
    __syncthreads();
    for (int r = tid; r < NROWS; r += 256) {
        int t = target[r];
        int c = (t < CUT1) ? -1 : (t < CUT2) ? 0 : (t < CUT3) ? 1 : 2;
        int s = -1;
        if (c >= 0) {
            s = atomicAdd(&lcnt[c], 1);
            rowmap[c * 1024 + s] = r;
        }
        slot[r] = s;
    }
    __syncthreads();
    if (tid < 3) cnt[tid] = lcnt[tid];
}

// ======================= MFMA GEMM body, BK=32, seg-major conflict-free LDS =======================
// TN: C[m][n] = sum_k A_bf16[m][k] * B_bf16[n][k]; BM=128; 4 waves 2x2 (64x64 each).
// Block covers NCOL col-tiles of 128 serially.
// MODE 0: store bf16 C (NCOL=1 only).
// MODE 1: pout[rbase + r] = sum over this block's cols of exp(C[r][n]+bias[n])  (NO atomics)
template<int MODE, int NCOL>
__device__ __forceinline__ void gemm_body(
    u16* __restrict__ As, u16* __restrict__ Bs,
    const u16* __restrict__ A, int lda, const int* __restrict__ rowmap,
    const u16* __restrict__ B, int ldb,
    const float* __restrict__ bias, int N, int K,
    u16* __restrict__ Cout, int ldc,
    float* __restrict__ pout, const int* __restrict__ count,
    int bx, int byg)
{
    const int tid = threadIdx.x;
    const int rbase = bx * 128;
    if (MODE == 1 && count) {
        int c = *count;
        if (rbase >= ((c + 127) & ~127)) return;   // inactive slots never read downstream
    }

    const int wave = tid >> 6, lane = tid & 63;
    const int l4 = lane & 15, quad = lane >> 4;
    const int wg = (wave >> 1) * 4;   // A row16-group base
    const int cg = (wave & 1) * 4;    // B col16-group base

    // staging slot indices: {tid, 256+tid}
    const int g0 = tid >> 6, seg0 = (tid >> 4) & 3, r0 = tid & 15;
    const int s1 = 256 + tid;
    const int g1 = s1 >> 6, seg1 = (s1 >> 4) & 3, r1 = s1 & 15;

    const u16 *Asrc0, *Asrc1;
    {
        int ar0 = rbase + g0 * 16 + r0, ar1 = rbase + g1 * 16 + r1;
        if (rowmap) { ar0 = rowmap[ar0]; ar1 = rowmap[ar1]; }
        Asrc0 = A + (size_t)ar0 * lda + seg0 * 8;
        Asrc1 = A + (size_t)ar1 * lda + seg1 * 8;
    }
    u16* Ad0 = &As[tid * 8]; u16* Ad1 = &As[(256 + tid) * 8];
    u16* Bd0 = &Bs[tid * 8]; u16* Bd1 = &Bs[(256 + tid) * 8];

    float part[4][4];
    if (MODE == 1) {
#pragma unroll
        for (int r = 0; r < 4; ++r)
#pragma unroll
            for (int g = 0; g < 4; ++g) part[r][g] = 0.f;
    }

    const int wr = wg * 16, wc = cg * 16;

    for (int ct = 0; ct < NCOL; ++ct) {
        const int cbase = (byg * NCOL + ct) * 128;
        int bc0 = cbase + g0 * 16 + r0; if (bc0 >= N) bc0 = N - 1;
        int bc1 = cbase + g1 * 16 + r1; if (bc1 >= N) bc1 = N - 1;
        const u16* Bsrc0 = B + (size_t)bc0 * ldb + seg0 * 8;
        const u16* Bsrc1 = B + (size_t)bc1 * ldb + seg1 * 8;

        f4 acc[4][4] = {};
        for (int kk = 0; kk < K; kk += 32) {
            gload16(Asrc0 + kk, Ad0);
            gload16(Asrc1 + kk, Ad1);
            gload16(Bsrc0 + kk, Bd0);
            gload16(Bsrc1 + kk, Bd1);
            __syncthreads();
            v8s af[4], bf[4];
#pragma unroll
            for (int r = 0; r < 4; ++r)
                af[r] = *(const v8s*)&As[((wg + r) * 64 + quad * 16 + l4) * 8];
#pragma unroll
            for (int c = 0; c < 4; ++c)
                bf[c] = *(const v8s*)&Bs[((cg + c) * 64 + quad * 16 + l4) * 8];
#pragma unroll
            for (int r = 0; r < 4; ++r)
#pragma unroll
                for (int c = 0; c < 4; ++c)
                    acc[r][c] = __builtin_amdgcn_mfma_f32_16x16x32_bf16(af[r], bf[c], acc[r][c], 0, 0, 0);
            __syncthreads();
        }

        if (MODE == 0) {
#pragma unroll
            for (int c = 0; c < 4; ++c) {
                int col = cbase + wc + c * 16 + l4;
                if (col < N) {
#pragma unroll
                    for (int r = 0; r < 4; ++r)
#pragma unroll
                        for (int g = 0; g < 4; ++g) {
                            int row = rbase + wr + r * 16 + quad * 4 + g;
                            Cout[(size_t)row * ldc + col] = f2b(acc[r][c][g]);
                        }
                }
            }
        } else {
#pragma unroll
            for (int c = 0; c < 4; ++c) {
                int col = cbase + wc + c * 16 + l4;
                if (col < N) {
                    float bb = bias[col];
#pragma unroll
                    for (int r = 0; r < 4; ++r)
#pragma unroll
                        for (int g = 0; g < 4; ++g)
                            part[r][g] += __expf(acc[r][c][g] + bb);
                }
            }
        }
    }

    if (MODE == 1) {
        // reduce across the 16 cols held by l4
#pragma unroll
        for (int off = 1; off < 16; off <<= 1)
#pragma unroll
            for (int r = 0; r < 4; ++r)
#pragma unroll
                for (int g = 0; g < 4; ++g)
                    part[r][g] += __shfl_xor(part[r][g], off);
        float v = part[0][0];
#pragma unroll
        for (int r = 0; r < 4; ++r)
#pragma unroll
            for (int g = 0; g < 4; ++g)
                if (l4 == r * 4 + g) v = part[r][g];
        // v = col-sum for row wr + rowoff, this wave's 64-col half
        int rowoff = (l4 >> 2) * 16 + quad * 4 + (l4 & 3);   // [0,64)
        float* lbuf = (float*)As;   // 256 floats (k-loop done with As)
        lbuf[(wave & 1) * 128 + wr + rowoff] = v;
        __syncthreads();
        if (tid < 128) pout[rbase + tid] = lbuf[tid] + lbuf[128 + tid];
    }
}

// ======================= fused W-cast + proj GEMM =======================
// blocks [0,88): proj = hidden @ [p0|p1|p2|p3]; [88,17852): W0..W3 fp32->bf16 casts
#define CP_E0 2559616
#define CP_E1 3199616
#define CP_E2 4479616
__global__ __launch_bounds__(256) void castproj_k(
    const u16* __restrict__ hb, const u16* __restrict__ pTb, u16* __restrict__ proj,
    const float* __restrict__ W0, const float* __restrict__ W1,
    const float* __restrict__ W2, const float* __restrict__ W3,
    u16* __restrict__ W0b, u16* __restrict__ W1b,
    u16* __restrict__ W2b, u16* __restrict__ W3b)
{
    __shared__ __align__(16) u16 As[4096];
    __shared__ __align__(16) u16 Bs[4096];
    int bid = blockIdx.x;
    if (bid < 88) {
        gemm_body<0, 1>(As, Bs, hb, 1024, nullptr, pTb, 1024, nullptr, 1360, 1024,
                        proj, LDP, nullptr, nullptr, bid & 7, bid >> 3);
        return;
    }
    int i = (bid - 88) * 256 + threadIdx.x;
    if (i < CP_E0) { cast8(W0, W0b, i); return; }
    if (i < CP_E1) { cast8(W1, W1b, i - CP_E0); return; }
    if (i < CP_E2) { cast8(W2, W2b, i - CP_E1); return; }
    int r = i - CP_E2;
    if (r >= 67738) return;
    // W3 [67738][16] -> bf16 padded to ld=32
    const float4* p = (const float4*)(W3 + (size_t)r * 16);
    float4 a = p[0], b = p[1], c = p[2], d = p[3];
    uint4 o0 = { pack2(a.x, a.y), pack2(a.z, a.w), pack2(b.x, b.y), pack2(b.z, b.w) };
    uint4 o1 = { pack2(c.x, c.y), pack2(c.z, c.w), pack2(d.x, d.y), pack2(d.z, d.w) };
    uint4 z = { 0, 0, 0, 0 };
    uint4* q = (uint4*)(W3b + (size_t)r * 32);
    q[0] = o0; q[1] = o1; q[2] = z; q[3] = z;
}

// ======================= fused sumexp: head + 3 tails, partial-store epilogue =======================
// regions: [0,1256) head NCOL=1; [1256,1576) t1 NCOL=4; [1576,2832) t2 NCOL=8; [2832,3368) t3 NCOL=8
#define SE_GRID 3368
__global__ __launch_bounds__(256) void sumexp_k(
    const u16* __restrict__ proj,
    const u16* __restrict__ W0b, const u16* __restrict__ W1b,
    const u16* __restrict__ W2b, const u16* __restrict__ W3b,
    const float* __restrict__ b0, const float* __restrict__ b1,
    const float* __restrict__ b2, const float* __restrict__ b3,
    float* __restrict__ Ph, float* __restrict__ Pt1,
    float* __restrict__ Pt2, float* __restrict__ Pt3,
    const int* __restrict__ rmap, const int* __restrict__ cnt)
{
    __shared__ __align__(16) u16 As[4096];
    __shared__ __align__(16) u16 Bs[4096];
    int bid = blockIdx.x;
    if (bid < 1256) {
        gemm_body<1, 1>(As, Bs, proj, LDP, nullptr, W0b, 1024, b0, CUT1, 1024,
                        nullptr, 0, Ph + (size_t)(bid >> 3) * 1024, nullptr, bid & 7, bid >> 3);
    } else if (bid < 1576) {
        int rel = bid - 1256;
        gemm_body<1, 4>(As, Bs, proj + 1024, LDP, rmap, W1b, 256, b1, 20000, 256,
                        nullptr, 0, Pt1 + (size_t)(rel >> 3) * 1024, cnt + 0, rel & 7, rel >> 3);
    } else if (bid < 2832) {
        int rel = bid - 1576;
        gemm_body<1, 8>(As, Bs, proj + 1280, LDP, rmap + 1024, W2b, 64, b2, 160000, 64,
                        nullptr, 0, Pt2 + (size_t)(rel >> 3) * 1024, cnt + 1, rel & 7, rel >> 3);
    } else {
        int rel = bid - 2832;
        gemm_body<1, 8>(As, Bs, proj + 1344, LDP, rmap + 2048, W3b, 32, b3, 67738, 32,
                        nullptr, 0, Pt3 + (size_t)(rel >> 3) * 1024, cnt + 2, rel & 7, rel >> 3);
    }
}

// ======================= fused gather + partial-reduce + finalize =======================
__global__ __launch_bounds__(256) void final_k(
    const u16* __restrict__ proj, const int* __restrict__ target, const int* __restrict__ slot,
    const float* __restrict__ cw, const float* __restrict__ cb,
    const float* __restrict__ W0, const float* __restrict__ b0,
    const float* __restrict__ W1, const float* __restrict__ b1,
    const float* __restrict__ W2, const float* __restrict__ b2,
    const float* __restrict__ W3, const float* __restrict__ b3,
    const float* __restrict__ Ph, const float* __restrict__ Pt1,
    const float* __restrict__ Pt2, const float* __restrict__ Pt3,
    float* __restrict__ out)
{
    int row = blockIdx.x * 4 + (threadIdx.x >> 6);
    int lane = threadIdx.x & 63;
    const u16* pr = proj + (size_t)row * LDP;

    // cluster logits
    float c0 = 0.f, c1 = 0.f, c2 = 0.f;
    for (int k = lane; k < 1024; k += 64) {
        float pv = b2f(pr[k]);
        c0 += pv * cw[k]; c1 += pv * cw[1024 + k]; c2 += pv * cw[2048 + k];
    }
    // head sumexp partials
    float hs = 0.f;
    for (int g = lane; g < NG_HEAD; g += 64) hs += Ph[g * 1024 + row];

    int t = target[row];
    const float* W; const float* bb; int K, off, rel;
    const float* Pc = Ph; int gc = 0;
    if (t < CUT1)      { W = W0; bb = b0; K = 1024; off = 0;    rel = t; }
    else if (t < CUT2) { W = W1; bb = b1; K = 256;  off = 1024; rel = t - CUT1; Pc = Pt1; gc = NG_T1; }
    else if (t < CUT3) { W = W2; bb = b2; K = 64;   off = 1280; rel = t - CUT2; Pc = Pt2; gc = NG_T2; }
    else               { W = W3; bb = b3; K = 16;   off = 1344; rel = t - CUT3; Pc = Pt3; gc = NG_T3; }

    // tail sumexp partials
    float ts = 0.f;
    int s = slot[row];
    if (s >= 0) {
        for (int g = lane; g < gc; g += 64) ts += Pc[g * 1024 + s];
    }
    // target logit
    float acc = 0.f;
    const float* wr = W + (size_t)rel * K;
    for (int k = lane; k < K; k += 64) acc += b2f(pr[off + k]) * wr[k];

#pragma unroll
    for (int o2 = 1; o2 < 64; o2 <<= 1) {
        c0 += __shfl_xor(c0, o2); c1 += __shfl_xor(c1, o2); c2 += __shfl_xor(c2, o2);
        hs += __shfl_xor(hs, o2); ts += __shfl_xor(ts, o2); acc += __shfl_xor(acc, o2);
    }

    if (lane == 0) {
        c0 += cb[0]; c1 += cb[1]; c2 += cb[2];
        float tl = acc + bb[rel];
        float lseh = __logf(hs + __expf(c0) + __expf(c1) + __expf(c2));
        float lp;
        if (t < CUT1) lp = tl - lseh;
        else {
            int c = (t < CUT2) ? 0 : (t < CUT3) ? 1 : 2;
            float cc = (c == 0) ? c0 : (c == 1) ? c1 : c2;
            lp = (cc - lseh) + (tl - __logf(ts));
        }
        out[row] = -lp;
    }
}

// ======================= fallback path (round-1, verified) =======================
__global__ void cast_bf16_k(const float* __restrict__ in, u16* __restrict__ out, int n8) {
    int i = blockIdx.x * 256 + threadIdx.x;
    if (i >= n8) return;
    cast8(in, out, i);
}

__global__ void transpose_f_k(const float* __restrict__ in, float* __restrict__ out, int d, int rowOff) {
    __shared__ float tile[32][33];
    int tx = threadIdx.x, ty = threadIdx.y;
    int x = blockIdx.x * 32 + tx;
    int ybase = blockIdx.y * 32;
#pragma unroll
    for (int j = 0; j < 4; ++j) {
        int r = ty + j * 8;
        tile[r][tx] = (x < d) ? in[(size_t)(ybase + r) * d + x] : 0.f;
    }
    __syncthreads();
#pragma unroll
    for (int j = 0; j < 4; ++j) {
        int x2 = blockIdx.x * 32 + ty + j * 8;
        if (x2 < d) out[(size_t)(rowOff + x2) * 1024 + ybase + tx] = tile[tx][ty + j * 8];
    }
}

__global__ __launch_bounds__(256) void gemm_tn_k(
    const u16* __restrict__ A, int lda,
    const float* __restrict__ B, int ldb,
    const float* __restrict__ bias, int N, int K,
    u16* __restrict__ Cout, int ldc, float* __restrict__ rowsum)
{
    int tid = threadIdx.x;
    int wave = tid >> 6, lane = tid & 63;
    int l4 = lane & 15, quad = lane >> 4;
    int rbase = blockIdx.x * 16;
    int cbase = blockIdx.y * 256 + wave * 64;

    f4 acc[4] = {};
    v8s zero8 = {0, 0, 0, 0, 0, 0, 0, 0};
    const u16* arow = A + (size_t)(rbase + l4) * lda;
    int nk = (K + 31) >> 5;
    for (int kt = 0; kt < nk; ++kt) {
        int kk = (kt << 5) + quad * 8;
        v8s a = (kk < K) ? *(const v8s*)(arow + kk) : zero8;
#pragma unroll
        for (int t = 0; t < 4; ++t) {
            int col = cbase + t * 16 + l4;
            v8s b = zero8;
            if ((col < N) && (kk < K)) {
                const float* bp = B + (size_t)col * ldb + kk;
                float4 f0 = *(const float4*)bp;
                float4 f1 = *(const float4*)(bp + 4);
                union { uint4 u; v8s s; } bu;
                bu.u.x = pack2(f0.x, f0.y); bu.u.y = pack2(f0.z, f0.w);
                bu.u.z = pack2(f1.x, f1.y); bu.u.w = pack2(f1.z, f1.w);
                b = bu.s;
            }
            acc[t] = __builtin_amdgcn_mfma_f32_16x16x32_bf16(a, b, acc[t], 0, 0, 0);
        }
    }
    if (Cout) {
#pragma unroll
        for (int t = 0; t < 4; ++t) {
            int col = cbase + t * 16 + l4;
            if (col < N) {
#pragma unroll
                for (int r = 0; r < 4; ++r)
                    Cout[(size_t)(rbase + quad * 4 + r) * ldc + col] = f2b(acc[t][r]);
            }
        }
    } else {
        float part[4] = {0.f, 0.f, 0.f, 0.f};
#pragma unroll
        for (int t = 0; t < 4; ++t) {
            int col = cbase + t * 16 + l4;
            if (col < N) {
                float bb = bias[col];
#pragma unroll
                for (int r = 0; r < 4; ++r) part[r] += __expf(acc[t][r] + bb);
            }
        }
#pragma unroll
        for (int off = 1; off < 16; off <<= 1)
#pragma unroll
            for (int r = 0; r < 4; ++r) part[r] += __shfl_xor(part[r], off);
        if (l4 < 4) {
            float v = (l4 == 0) ? part[0] : (l4 == 1) ? part[1] : (l4 == 2) ? part[2] : part[3];
            atomicAdd(&rowsum[rbase + quad * 4 + l4], v);
        }
    }
}

__global__ __launch_bounds__(256) void gather_k(
    const u16* __restrict__ proj, const int* __restrict__ target,
    const float* __restrict__ cw, const float* __restrict__ cb,
    const float* __restrict__ W0, const float* __restrict__ b0,
    const float* __restrict__ W1, const float* __restrict__ b1,
    const float* __restrict__ W2, const float* __restrict__ b2,
    const float* __restrict__ W3, const float* __restrict__ b3,
    float* __restrict__ rs_head, float* __restrict__ cl, float* __restrict__ tl)
{
    int row = blockIdx.x * 4 + (threadIdx.x >> 6);
    int lane = threadIdx.x & 63;
    const u16* pr = proj + (size_t)row * LDP;

    float c0 = 0.f, c1 = 0.f, c2 = 0.f;
    for (int k = lane; k < 1024; k += 64) {
        float pv = b2f(pr[k]);
        c0 += pv * cw[k]; c1 += pv * cw[1024 + k]; c2 += pv * cw[2048 + k];
    }
#pragma unroll
    for (int off = 1; off < 64; off <<= 1) {
        c0 += __shfl_xor(c0, off); c1 += __shfl_xor(c1, off); c2 += __shfl_xor(c2, off);
    }
    int t = target[row];
    const float* W; const float* bb; int K, off, rel;
    if (t < CUT1)      { W = W0; bb = b0; K = 1024; off = 0;    rel = t; }
    else if (t < CUT2) { W = W1; bb = b1; K = 256;  off = 1024; rel = t - CUT1; }
    else if (t < CUT3) { W = W2; bb = b2; K = 64;   off = 1280; rel = t - CUT2; }
    else               { W = W3; bb = b3; K = 16;   off = 1344; rel = t - CUT3; }
    float acc = 0.f;
    const float* wr = W + (size_t)rel * K;
    for (int k = lane; k < K; k += 64) acc += b2f(pr[off + k]) * wr[k];
#pragma unroll
    for (int o2 = 1; o2 < 64; o2 <<= 1) acc += __shfl_xor(acc, o2);
    if (lane == 0) {
        c0 += cb[0]; c1 += cb[1]; c2 += cb[2];
        cl[row * 3 + 0] = c0; cl[row * 3 + 1] = c1; cl[row * 3 + 2] = c2;
        atomicAdd(&rs_head[row], __expf(c0) + __expf(c1) + __expf(c2));
        tl[row] = acc + bb[rel];
    }
}

__global__ void finalize_full_k(const int* __restrict__ target, const float* __restrict__ rs,
                                const float* __restrict__ cl, const float* __restrict__ tl,
                                float* __restrict__ out)
{
    int i = blockIdx.x * 256 + threadIdx.x;
    if (i >= NROWS) return;
    int t = target[i];
    float lseh = __logf(rs[i]);
    float lp;
    if (t < CUT1) lp = tl[i] - lseh;
    else {
        int c = (t < CUT2) ? 0 : (t < CUT3) ? 1 : 2;
        lp = (cl[i * 3 + c] - lseh) + (tl[i] - __logf(rs[(c + 1) * 1024 + i]));
    }
    out[i] = -lp;
}

// ======================= host =======================
extern "C" void kernel_launch(void* const* d_in, const int* in_sizes, int n_in,
                              void* d_out, int out_size, void* d_ws, size_t ws_size,
                              hipStream_t stream)
{
    const float* hidden = (const float*)d_in[0];
    const int*   target = (const int*)d_in[1];
    const float* W0 = (const float*)d_in[2];
    const float* b0 = (const float*)d_in[3];
    const float* p0 = (const float*)d_in[4];
    const float* W1 = (const float*)d_in[5];
    const float* b1 = (const float*)d_in[6];
    const float* p1 = (const float*)d_in[7];
    const float* W2 = (const float*)d_in[8];
    const float* b2 = (const float*)d_in[9];
    const float* p2 = (const float*)d_in[10];
    const float* W3 = (const float*)d_in[11];
    const float* b3 = (const float*)d_in[12];
    const float* p3 = (const float*)d_in[13];
    const float* cw = (const float*)d_in[14];
    const float* cb = (const float*)d_in[15];
    float* out = (float*)d_out;
    char* w = (char*)d_ws;

    if (ws_size >= 84000000ull) {
        // ---- fast path ----
        // phase A buffers (prep/castproj): hb [0,2097152), pTb [2097152,4882432)
        // phase B buffers (sumexp/final): partials recycle the hb/pTb region
        u16*   hb   = (u16*)(w + 0);             // 1024x1024 bf16
        u16*   pTb  = (u16*)(w + 2097152);       // [1360][1024] bf16
        float* Ph   = (float*)(w + 0);           // [157][1024] f32 (recycles hb)
        float* Pt1  = (float*)(w + 643072);      // [40][1024]
        float* Pt2  = (float*)(w + 806912);      // [157][1024]
        float* Pt3  = (float*)(w + 1449984);     // [67][1024]   (ends 1724416 < 2097152)
        u16*   proj = (u16*)(w + 4882432);       // [1024][1360] bf16
        u16*   W0b  = (u16*)(w + 7667712);       // 19997x1024
        u16*   W1b  = (u16*)(w + 48621568);      // 20000x256
        u16*   W2b  = (u16*)(w + 58861568);      // 160000x64
        u16*   W3b  = (u16*)(w + 79341568);      // 67738x32 (zero-padded k16..31)
        int*   cnt  = (int*)(w + 83693184);      // 3 (+pad)
        int*   slot = (int*)(w + 83693200);      // 1024
        int*   rmap = (int*)(w + 83697296);      // 3x1024

        prep_small_k<<<1889, 256, 0, stream>>>(hidden, p0, p1, p2, p3, target,
                                               hb, pTb, cnt, slot, rmap);

        castproj_k<<<17852, 256, 0, stream>>>(hb, pTb, proj,
                                              W0, W1, W2, W3, W0b, W1b, W2b, W3b);

        sumexp_k<<<SE_GRID, 256, 0, stream>>>(proj, W0b, W1b, W2b, W3b,
                                              b0, b1, b2, b3,
                                              Ph, Pt1, Pt2, Pt3, rmap, cnt);

        final_k<<<256, 256, 0, stream>>>(proj, target, slot, cw, cb,
                                         W0, b0, W1, b1, W2, b2, W3, b3,
                                         Ph, Pt1, Pt2, Pt3, out);
    } else {
        // ---- round-1 verified fallback ----
        float* pT   = (float*)w;                          // [1360][1024] f32
        u16*   hb   = (u16*)(w + 5570560);                // [1024][1024] bf16
        u16*   proj = (u16*)(w + 7667712);                // [1024][1360] bf16
        float* rs   = (float*)(w + 10452992);
        float* cl   = (float*)(w + 10469376);
        float* tl   = (float*)(w + 10481664);
        dim3 tb(32, 8);

        hipMemsetAsync(rs, 0, 4 * 1024 * sizeof(float), stream);
        cast_bf16_k<<<512, 256, 0, stream>>>(hidden, hb, 131072);
        transpose_f_k<<<dim3(32, 32), tb, 0, stream>>>(p0, pT, 1024, 0);
        transpose_f_k<<<dim3(8, 32),  tb, 0, stream>>>(p1, pT, 256, 1024);
        transpose_f_k<<<dim3(2, 32),  tb, 0, stream>>>(p2, pT, 64, 1280);
        transpose_f_k<<<dim3(1, 32),  tb, 0, stream>>>(p3, pT, 16, 1344);

        gemm_tn_k<<<dim3(64, 6), 256, 0, stream>>>(hb, 1024, pT, 1024, nullptr,
                                                   1360, 1024, proj, LDP, nullptr);
        gemm_tn_k<<<dim3(64, 79), 256, 0, stream>>>(proj, LDP, W0, 1024, b0,
                                                    CUT1, 1024, nullptr, 0, rs);
        gemm_tn_k<<<dim3(64, 79), 256, 0, stream>>>(proj + 1024, LDP, W1, 256, b1,
                                                    20000, 256, nullptr, 0, rs + 1024);
        gemm_tn_k<<<dim3(64, 625), 256, 0, stream>>>(proj + 1280, LDP, W2, 64, b2,
                                                     160000, 64, nullptr, 0, rs + 2048);
        gemm_tn_k<<<dim3(64, 265), 256, 0, stream>>>(proj + 1344, LDP, W3, 16, b3,
                                                     67738, 16, nullptr, 0, rs + 3072);

        gather_k<<<256, 256, 0, stream>>>(proj, target, cw, cb,
                                          W0, b0, W1, b1, W2, b2, W3, b3, rs, cl, tl);
        finalize_full_k<<<4, 256, 0, stream>>>(target, rs, cl, tl, out);
    }
}